// Round 1
// baseline (2201.305 us; speedup 1.0000x reference)
//
#include <hip/hip_runtime.h>
#include <hip/hip_bf16.h>
#include <math.h>

// Model: SIREN eigenfunction banks + small linear head.
// B=32, T_IN=512, T_OUT=256, C=64, NB=16 -> E=1024, D=128, L=3
// Input order (setup_inputs dict order):
// 0 x_enc (32,512,64) 1 x_mark_enc (32,512,4) 2 x_dec 3 x_mark_dec
// 4 W0_in (1024,128,1) 5 b0_in (1024,128) 6 Wh_in (2,1024,128,128)
// 7 bh_in (2,1024,128) 8 Wl_in (1024,1,128) 9 bl_in (1024,1) 10 w0i_in (1024)
// 11..17 same for _out, 18 Wlin (1088,1092), 19 blin (1088)
// Output: (32,256,64) float32

constexpr int DD    = 128;
constexpr int E_TOT = 1024;
constexpr int T_INc = 512;
constexpr int T_OUTc= 256;
constexpr int BBc   = 32;
constexpr int CCc   = 64;
constexpr int NB1   = 17;            // nb + 1
constexpr int EF_W  = NB1 * CCc;     // 1088
constexpr int LIN_I = EF_W + 4;      // 1092
constexpr int LIN_O = EF_W;          // 1088

// ---------------------------------------------------------------------------
// eigen_kernel: one block per (t-tile of TT, e). Computes the raw SIREN output
// y_f[t,e] and writes it (un-normalized) into efn[t][64 + e] (slot layout:
// efn[t][n*64+c], n=0 row filled by normalize_kernel with 1/norm).
// LDS: WT [128][132] transposed weight tile, xA/xB [128][TT+4] transposed acts.
// ---------------------------------------------------------------------------
template<int T, int TT>
__global__ __launch_bounds__(256) void eigen_kernel(
    const float* __restrict__ W0, const float* __restrict__ b0,
    const float* __restrict__ Wh, const float* __restrict__ bh,
    const float* __restrict__ Wl, const float* __restrict__ bl,
    const float* __restrict__ w0i, float* __restrict__ efn)
{
  constexpr int SW = 132;      // padded row stride for WT (528B, 16B aligned)
  constexpr int SX = TT + 4;   // padded row stride for xT  (272B, 16B aligned)
  const int e   = blockIdx.y;
  const int t0  = blockIdx.x * TT;
  const int tid = threadIdx.x;

  extern __shared__ float lds[];
  float* WT = lds;                 // [128][SW]
  float* xA = lds + DD * SW;       // [128][SX]
  float* xB = xA + DD * SX;        // [128][SX]

  // ---- layer 0: x0[d][t] = sin(w0i * (W0[e,d]*dom(t) + b0[e,d])) ----
  {
    const int d = tid & 127;
    const int h = tid >> 7;
    const float w0 = W0[e * DD + d];
    const float bb = b0[e * DD + d];
    const float wi = w0i[e];
    const float step = 1.0f / (float)(T - 1);
    for (int k = 0; k < TT / 2; ++k) {
      const int tl = h * (TT / 2) + k;
      const float dom = (float)(t0 + tl) * step;
      xA[d * SX + tl] = sinf(wi * (w0 * dom + bb));
    }
  }

  const int og = tid & 31;   // o-group: owns o = og*4 .. og*4+3
  const int tg = tid >> 5;   // t-group: owns t = tg*8 .. tg*8+7

  // ---- two hidden layers ----
  for (int l = 0; l < 2; ++l) {
    __syncthreads();   // prev compute done reading WT / x buffers
    // stage Wh[l,e] transposed into WT (coalesced global float4 reads)
    const float* Wg = Wh + ((size_t)l * E_TOT + e) * (DD * DD);
    #pragma unroll
    for (int k = 0; k < 16; ++k) {
      const int f = k * 256 + tid;
      const int w = f * 4;
      const int o = w >> 7;          // 0..127
      const int i = w & 127;         // multiple of 4
      const float4 v = *reinterpret_cast<const float4*>(Wg + w);
      WT[(i + 0) * SW + o] = v.x;
      WT[(i + 1) * SW + o] = v.y;
      WT[(i + 2) * SW + o] = v.z;
      WT[(i + 3) * SW + o] = v.w;
    }
    __syncthreads();

    const float* xin  = (l == 0) ? xA : xB;
    float*       xout = (l == 0) ? xB : xA;

    float acc[4][8];
    #pragma unroll
    for (int a = 0; a < 4; ++a)
      #pragma unroll
      for (int b = 0; b < 8; ++b) acc[a][b] = 0.0f;

    #pragma unroll 4
    for (int i = 0; i < DD; ++i) {
      const float4 w4  = *reinterpret_cast<const float4*>(&WT[i * SW + og * 4]);
      const float4 x0v = *reinterpret_cast<const float4*>(&xin[i * SX + tg * 8]);
      const float4 x1v = *reinterpret_cast<const float4*>(&xin[i * SX + tg * 8 + 4]);
      const float wv[4] = {w4.x, w4.y, w4.z, w4.w};
      const float xv[8] = {x0v.x, x0v.y, x0v.z, x0v.w, x1v.x, x1v.y, x1v.z, x1v.w};
      #pragma unroll
      for (int a = 0; a < 4; ++a)
        #pragma unroll
        for (int b = 0; b < 8; ++b)
          acc[a][b] += wv[a] * xv[b];
    }

    const float* bhp = bh + ((size_t)l * E_TOT + e) * DD + og * 4;
    const float bhv[4] = {bhp[0], bhp[1], bhp[2], bhp[3]};
    #pragma unroll
    for (int a = 0; a < 4; ++a)
      #pragma unroll
      for (int b = 0; b < 8; ++b)
        xout[(og * 4 + a) * SX + tg * 8 + b] = sinf(acc[a][b] + bhv[a]);
  }
  __syncthreads();

  // ---- final layer: y[t] = Wl[e,:] . x2[:,t] + bl[e] ----  (x2 lives in xA)
  if (tid < TT) {
    const int tl = tid;
    float acc = bl[e];
    #pragma unroll 4
    for (int i = 0; i < DD; ++i)
      acc += Wl[e * DD + i] * xA[i * SX + tl];
    efn[(size_t)(t0 + tl) * EF_W + CCc + e] = acc;
  }
}

// ---------------------------------------------------------------------------
// normalize: per (t,c): norm = sqrt(1 + sum_n y[n]^2); row[0*64+c] = 1/norm,
// row[n*64+c] *= 1/norm. In place on efn.
// ---------------------------------------------------------------------------
__global__ void normalize_kernel(float* __restrict__ efn)
{
  const int t = blockIdx.x;
  const int c = threadIdx.x;   // 64
  float* row = efn + (size_t)t * EF_W;
  float v[16];
  float s = 1.0f;
  #pragma unroll
  for (int n = 0; n < 16; ++n) {
    v[n] = row[CCc + n * CCc + c];
    s += v[n] * v[n];
  }
  const float inv = 1.0f / sqrtf(s);
  row[c] = inv;
  #pragma unroll
  for (int n = 0; n < 16; ++n)
    row[CCc + n * CCc + c] = v[n] * inv;
}

// ---------------------------------------------------------------------------
// coeffs + label concat: flat_in[b][n*64+c] = sum_t x_enc[b,t,c]*efn_in[t,n,c]
// flat_in[b][1088..1091] = x_mark_enc[b, T_IN-1, :]
// ---------------------------------------------------------------------------
__global__ void coeffs_kernel(const float* __restrict__ x_enc,
                              const float* __restrict__ x_mark_enc,
                              const float* __restrict__ efn_in,
                              float* __restrict__ flat_in)
{
  const int n = blockIdx.x;   // 17
  const int b = blockIdx.y;   // 32
  const int c = threadIdx.x;  // 64
  float acc = 0.0f;
  for (int t = 0; t < T_INc; ++t)
    acc += x_enc[((size_t)b * T_INc + t) * CCc + c]
         * efn_in[(size_t)t * EF_W + n * CCc + c];
  flat_in[b * LIN_I + n * CCc + c] = acc;
  if (n == 0 && c < 4)
    flat_in[b * LIN_I + EF_W + c] =
        x_mark_enc[((size_t)b * T_INc + (T_INc - 1)) * 4 + c];
}

// ---------------------------------------------------------------------------
// linear: pred[b][o] = blin[o] + sum_j Wlin[o][j] * flat_in[b][j]
// ---------------------------------------------------------------------------
__global__ void linear_kernel(const float* __restrict__ flat_in,
                              const float* __restrict__ Wlin,
                              const float* __restrict__ blin,
                              float* __restrict__ pred)
{
  const int o = blockIdx.x * 64 + threadIdx.x;  // 17*64 = 1088
  const int b = blockIdx.y;                     // 32
  const float* w  = Wlin + (size_t)o * LIN_I;
  const float* xi = flat_in + b * LIN_I;
  float acc = blin[o];
  for (int j = 0; j < LIN_I; ++j) acc += w[j] * xi[j];
  pred[b * LIN_O + o] = acc;
}

// ---------------------------------------------------------------------------
// recon: out[b,t,c] = sum_n pred[b][n*64+c] * efn_out[t][n*64+c]
// ---------------------------------------------------------------------------
__global__ void recon_kernel(const float* __restrict__ pred,
                             const float* __restrict__ efn_out,
                             float* __restrict__ out)
{
  const int b = blockIdx.y;
  const int t = blockIdx.x * 4 + (threadIdx.x >> 6);
  const int c = threadIdx.x & 63;
  float acc = 0.0f;
  #pragma unroll
  for (int n = 0; n < NB1; ++n)
    acc += pred[b * LIN_O + n * CCc + c]
         * efn_out[(size_t)t * EF_W + n * CCc + c];
  out[((size_t)b * T_OUTc + t) * CCc + c] = acc;
}

// ---------------------------------------------------------------------------
extern "C" void kernel_launch(void* const* d_in, const int* in_sizes, int n_in,
                              void* d_out, int out_size, void* d_ws, size_t ws_size,
                              hipStream_t stream)
{
  const float* x_enc      = (const float*)d_in[0];
  const float* x_mark_enc = (const float*)d_in[1];
  const float* W0_in  = (const float*)d_in[4];
  const float* b0_in  = (const float*)d_in[5];
  const float* Wh_in  = (const float*)d_in[6];
  const float* bh_in  = (const float*)d_in[7];
  const float* Wl_in  = (const float*)d_in[8];
  const float* bl_in  = (const float*)d_in[9];
  const float* w0i_in = (const float*)d_in[10];
  const float* W0_out  = (const float*)d_in[11];
  const float* b0_out  = (const float*)d_in[12];
  const float* Wh_out  = (const float*)d_in[13];
  const float* bh_out  = (const float*)d_in[14];
  const float* Wl_out  = (const float*)d_in[15];
  const float* bl_out  = (const float*)d_in[16];
  const float* w0i_out = (const float*)d_in[17];
  const float* Wlin = (const float*)d_in[18];
  const float* blin = (const float*)d_in[19];

  float* ws      = (float*)d_ws;
  float* efn_in  = ws;                                   // 512*1088
  float* efn_out = efn_in + (size_t)T_INc * EF_W;        // 256*1088
  float* flat_in = efn_out + (size_t)T_OUTc * EF_W;      // 32*1092
  float* pred    = flat_in + (size_t)BBc * LIN_I;        // 32*1088

  constexpr int TT = 64;
  const size_t shmem = (size_t)(DD * 132 + 2 * DD * (TT + 4)) * sizeof(float); // 137216 B

  hipFuncSetAttribute(reinterpret_cast<const void*>(&eigen_kernel<T_INc, TT>),
                      hipFuncAttributeMaxDynamicSharedMemorySize, (int)shmem);
  hipFuncSetAttribute(reinterpret_cast<const void*>(&eigen_kernel<T_OUTc, TT>),
                      hipFuncAttributeMaxDynamicSharedMemorySize, (int)shmem);

  eigen_kernel<T_INc, TT><<<dim3(T_INc / TT, E_TOT), dim3(256), shmem, stream>>>(
      W0_in, b0_in, Wh_in, bh_in, Wl_in, bl_in, w0i_in, efn_in);
  eigen_kernel<T_OUTc, TT><<<dim3(T_OUTc / TT, E_TOT), dim3(256), shmem, stream>>>(
      W0_out, b0_out, Wh_out, bh_out, Wl_out, bl_out, w0i_out, efn_out);

  normalize_kernel<<<dim3(T_INc),  dim3(64), 0, stream>>>(efn_in);
  normalize_kernel<<<dim3(T_OUTc), dim3(64), 0, stream>>>(efn_out);

  coeffs_kernel<<<dim3(NB1, BBc), dim3(64), 0, stream>>>(x_enc, x_mark_enc, efn_in, flat_in);
  linear_kernel<<<dim3(NB1, BBc), dim3(64), 0, stream>>>(flat_in, Wlin, blin, pred);
  recon_kernel<<<dim3(T_OUTc / 4, BBc), dim3(256), 0, stream>>>(pred, efn_out, (float*)d_out);
}

// Round 3
// 915.748 us; speedup vs baseline: 2.4038x; 2.4038x over previous
//
#include <hip/hip_runtime.h>
#include <hip/hip_bf16.h>
#include <math.h>

// SIREN eigenfunction banks + small linear head, MFMA bf16 hidden layers.
// B=32, T_IN=512, T_OUT=256, C=64, NB=16 -> E=1024, D=128, L=3
// Inputs: 0 x_enc 1 x_mark_enc 2 x_dec 3 x_mark_dec
// 4 W0_in 5 b0_in 6 Wh_in 7 bh_in 8 Wl_in 9 bl_in 10 w0i_in
// 11..17 same _out, 18 Wlin (1088,1092), 19 blin (1088). Out: (32,256,64) f32.

typedef short  bf16x8 __attribute__((ext_vector_type(8)));
typedef float  f32x4  __attribute__((ext_vector_type(4)));
typedef unsigned short u16;
typedef u16    u16x4  __attribute__((ext_vector_type(4)));

constexpr int DD    = 128;
constexpr int E_TOT = 1024;
constexpr int T_INc = 512;
constexpr int T_OUTc= 256;
constexpr int BBc   = 32;
constexpr int CCc   = 64;
constexpr int NB1   = 17;
constexpr int EF_W  = NB1 * CCc;     // 1088
constexpr int LIN_I = EF_W + 4;      // 1092
constexpr int LIN_O = EF_W;          // 1088

// bf16 RNE round + exact widen
__device__ __forceinline__ u16 f2b(float f) {
  unsigned u = __builtin_bit_cast(unsigned, f);
  unsigned r = (u + 0x7FFFu + ((u >> 16) & 1u)) >> 16;
  return (u16)r;
}
__device__ __forceinline__ float b2f(u16 u) {
  unsigned v = ((unsigned)u) << 16;
  return __builtin_bit_cast(float, v);
}

// XOR-swizzled element index into a row-major [rows][128] u16 LDS plane.
// byte = row*256 + col*2 ; byte ^= (row&7)<<4  (T2 recipe, preserves 16B chunks)
__device__ __forceinline__ int swz(int row, int col) {
  return row * DD + ((((col << 1) ^ ((row & 7) << 4)) >> 1));
}

// ---------------------------------------------------------------------------
// eigen_mfma: block = (e, 64-t tile). LDS (u16 elems):
//   W1 @0 (16384), W2 @16384, xAhi @32768, xAlo @40960, xBhi @49152, xBlo @57344
// Hidden layers: out[t][o] = sin( sum_i W[o][i] * x[t][i] + bh[o] ) via
// mfma_f32_16x16x32_bf16 with x split hi/lo (2 MFMAs per acc tile).
// ---------------------------------------------------------------------------
template<int T>
__global__ __launch_bounds__(256) void eigen_mfma(
    const float* __restrict__ W0, const float* __restrict__ b0,
    const float* __restrict__ Wh, const float* __restrict__ bh,
    const float* __restrict__ Wl, const float* __restrict__ bl,
    const float* __restrict__ w0i, float* __restrict__ efn)
{
  constexpr int NT = T / 64;
  extern __shared__ u16 lds[];
  u16* xAhi = lds + 32768;
  u16* xAlo = lds + 40960;
  u16* xBhi = lds + 49152;
  u16* xBlo = lds + 57344;

  // XCD-bijective swizzle: same-e t-tiles land on the same XCD, consecutively.
  const int b  = blockIdx.x;
  const int e  = (b & 7) + 8 * ((b >> 3) / NT);
  const int t0 = ((b >> 3) % NT) * 64;

  const int tid  = threadIdx.x;
  const int lane = tid & 63;

  // ---- stage W1, W2 -> LDS bf16 (swizzled) ----
  for (int l = 0; l < 2; ++l) {
    const float* Wg = Wh + ((size_t)l * E_TOT + e) * (DD * DD);
    u16* Wd = lds + l * 16384;
    #pragma unroll
    for (int k = 0; k < 16; ++k) {
      const int f = k * 256 + tid;          // float4 index
      const int o = f >> 5;                 // row (32 float4 per row)
      const int i = (f & 31) * 4;           // col elem
      const float4 v = *reinterpret_cast<const float4*>(Wg + (size_t)f * 4);
      u16x4 p;
      p[0] = f2b(v.x); p[1] = f2b(v.y); p[2] = f2b(v.z); p[3] = f2b(v.w);
      *reinterpret_cast<u16x4*>(&Wd[swz(o, i)]) = p;
    }
  }

  // ---- layer 0: xA[t][d] = sin(w0i*(W0[d]*dom + b0[d])), split hi/lo ----
  {
    const int t = tid >> 2;
    const int q = tid & 3;
    const float dom = (float)(t0 + t) * (1.0f / (float)(T - 1));
    const float wi  = w0i[e];
    #pragma unroll
    for (int c = 0; c < 8; ++c) {
      const int d = q * 32 + c * 4;
      const float4 w4 = *reinterpret_cast<const float4*>(W0 + (size_t)e * DD + d);
      const float4 b4 = *reinterpret_cast<const float4*>(b0 + (size_t)e * DD + d);
      float xs[4] = { sinf(wi * (w4.x * dom + b4.x)),
                      sinf(wi * (w4.y * dom + b4.y)),
                      sinf(wi * (w4.z * dom + b4.z)),
                      sinf(wi * (w4.w * dom + b4.w)) };
      u16x4 hh, ll;
      #pragma unroll
      for (int j = 0; j < 4; ++j) {
        const u16 h = f2b(xs[j]);
        const u16 lo = f2b(xs[j] - b2f(h));
        hh[j] = h;
        ll[j] = lo;
      }
      *reinterpret_cast<u16x4*>(&xAhi[swz(t, d)]) = hh;
      *reinterpret_cast<u16x4*>(&xAlo[swz(t, d)]) = ll;
    }
  }
  __syncthreads();

  // ---- hidden layers (MFMA) ----
  const int wv = tid >> 6;        // wave 0..3
  const int wt = wv >> 1;         // t-group: rows wt*32..+32
  const int wo = wv & 1;          // o-group: cols wo*64..+64
  const int lm = lane & 15;
  const int lg = lane >> 4;

  for (int l = 0; l < 2; ++l) {
    const u16* Wd  = lds + l * 16384;
    const u16* xih = (l == 0) ? xAhi : xBhi;
    const u16* xil = (l == 0) ? xAlo : xBlo;
    u16*       xoh = (l == 0) ? xBhi : xAhi;
    u16*       xol = (l == 0) ? xBlo : xAlo;

    float bhv[4];
    #pragma unroll
    for (int n = 0; n < 4; ++n)
      bhv[n] = bh[((size_t)l * E_TOT + e) * DD + wo * 64 + n * 16 + lm];

    f32x4 acc[2][4];
    #pragma unroll
    for (int m = 0; m < 2; ++m)
      #pragma unroll
      for (int n = 0; n < 4; ++n) acc[m][n] = (f32x4){0.f, 0.f, 0.f, 0.f};

    #pragma unroll
    for (int kk = 0; kk < 4; ++kk) {
      const int kb = kk * 32 + lg * 8;
      bf16x8 ah[2], al[2], bw[4];
      #pragma unroll
      for (int m = 0; m < 2; ++m) {
        const int r = wt * 32 + m * 16 + lm;
        ah[m] = *reinterpret_cast<const bf16x8*>(&xih[swz(r, kb)]);
        al[m] = *reinterpret_cast<const bf16x8*>(&xil[swz(r, kb)]);
      }
      #pragma unroll
      for (int n = 0; n < 4; ++n) {
        const int o = wo * 64 + n * 16 + lm;
        bw[n] = *reinterpret_cast<const bf16x8*>(&Wd[swz(o, kb)]);
      }
      #pragma unroll
      for (int m = 0; m < 2; ++m)
        #pragma unroll
        for (int n = 0; n < 4; ++n)
          acc[m][n] = __builtin_amdgcn_mfma_f32_16x16x32_bf16(ah[m], bw[n], acc[m][n], 0, 0, 0);
      #pragma unroll
      for (int m = 0; m < 2; ++m)
        #pragma unroll
        for (int n = 0; n < 4; ++n)
          acc[m][n] = __builtin_amdgcn_mfma_f32_16x16x32_bf16(al[m], bw[n], acc[m][n], 0, 0, 0);
    }

    // activation + split + write (C/D layout: col = lane&15, row = lg*4 + r)
    #pragma unroll
    for (int m = 0; m < 2; ++m)
      #pragma unroll
      for (int n = 0; n < 4; ++n) {
        const int o = wo * 64 + n * 16 + lm;
        #pragma unroll
        for (int r = 0; r < 4; ++r) {
          const int t = wt * 32 + m * 16 + lg * 4 + r;
          const float act = sinf(acc[m][n][r] + bhv[n]);
          const u16 h  = f2b(act);
          const u16 lo = f2b(act - b2f(h));
          xoh[swz(t, o)] = h;
          xol[swz(t, o)] = lo;
        }
      }
    __syncthreads();
  }

  // ---- final layer: y[t] = Wl[e,:] . x2[:,t] + bl[e]  (x2 = xA hi+lo) ----
  {
    const int t = tid >> 2;
    const int q = tid & 3;
    float acc = 0.0f;
    #pragma unroll
    for (int c = 0; c < 4; ++c) {
      const int i = q * 32 + c * 8;
      const bf16x8 hv = *reinterpret_cast<const bf16x8*>(&xAhi[swz(t, i)]);
      const bf16x8 lv = *reinterpret_cast<const bf16x8*>(&xAlo[swz(t, i)]);
      #pragma unroll
      for (int j = 0; j < 8; ++j) {
        const float x = b2f((u16)hv[j]) + b2f((u16)lv[j]);
        acc += Wl[(size_t)e * DD + i + j] * x;
      }
    }
    acc += __shfl_xor(acc, 1);
    acc += __shfl_xor(acc, 2);
    if (q == 0)
      efn[(size_t)(t0 + t) * EF_W + CCc + e] = acc + bl[e];
  }
}

// ---------------------------------------------------------------------------
__global__ void normalize_kernel(float* __restrict__ efn)
{
  const int t = blockIdx.x;
  const int c = threadIdx.x;   // 64
  float* row = efn + (size_t)t * EF_W;
  float v[16];
  float s = 1.0f;
  #pragma unroll
  for (int n = 0; n < 16; ++n) {
    v[n] = row[CCc + n * CCc + c];
    s += v[n] * v[n];
  }
  const float inv = 1.0f / sqrtf(s);
  row[c] = inv;
  #pragma unroll
  for (int n = 0; n < 16; ++n)
    row[CCc + n * CCc + c] = v[n] * inv;
}

__global__ void coeffs_kernel(const float* __restrict__ x_enc,
                              const float* __restrict__ x_mark_enc,
                              const float* __restrict__ efn_in,
                              float* __restrict__ flat_in)
{
  const int n = blockIdx.x;   // 17
  const int b = blockIdx.y;   // 32
  const int c = threadIdx.x;  // 64
  float acc = 0.0f;
  for (int t = 0; t < T_INc; ++t)
    acc += x_enc[((size_t)b * T_INc + t) * CCc + c]
         * efn_in[(size_t)t * EF_W + n * CCc + c];
  flat_in[b * LIN_I + n * CCc + c] = acc;
  if (n == 0 && c < 4)
    flat_in[b * LIN_I + EF_W + c] =
        x_mark_enc[((size_t)b * T_INc + (T_INc - 1)) * 4 + c];
}

__global__ void linear_kernel(const float* __restrict__ flat_in,
                              const float* __restrict__ Wlin,
                              const float* __restrict__ blin,
                              float* __restrict__ pred)
{
  const int o = blockIdx.x * 64 + threadIdx.x;  // 1088
  const int b = blockIdx.y;                     // 32
  const float* w  = Wlin + (size_t)o * LIN_I;
  const float* xi = flat_in + b * LIN_I;
  float acc = blin[o];
  for (int j = 0; j < LIN_I; ++j) acc += w[j] * xi[j];
  pred[b * LIN_O + o] = acc;
}

__global__ void recon_kernel(const float* __restrict__ pred,
                             const float* __restrict__ efn_out,
                             float* __restrict__ out)
{
  const int b = blockIdx.y;
  const int t = blockIdx.x * 4 + (threadIdx.x >> 6);
  const int c = threadIdx.x & 63;
  float acc = 0.0f;
  #pragma unroll
  for (int n = 0; n < NB1; ++n)
    acc += pred[b * LIN_O + n * CCc + c]
         * efn_out[(size_t)t * EF_W + n * CCc + c];
  out[((size_t)b * T_OUTc + t) * CCc + c] = acc;
}

// ---------------------------------------------------------------------------
extern "C" void kernel_launch(void* const* d_in, const int* in_sizes, int n_in,
                              void* d_out, int out_size, void* d_ws, size_t ws_size,
                              hipStream_t stream)
{
  const float* x_enc      = (const float*)d_in[0];
  const float* x_mark_enc = (const float*)d_in[1];
  const float* W0_in  = (const float*)d_in[4];
  const float* b0_in  = (const float*)d_in[5];
  const float* Wh_in  = (const float*)d_in[6];
  const float* bh_in  = (const float*)d_in[7];
  const float* Wl_in  = (const float*)d_in[8];
  const float* bl_in  = (const float*)d_in[9];
  const float* w0i_in = (const float*)d_in[10];
  const float* W0_out  = (const float*)d_in[11];
  const float* b0_out  = (const float*)d_in[12];
  const float* Wh_out  = (const float*)d_in[13];
  const float* bh_out  = (const float*)d_in[14];
  const float* Wl_out  = (const float*)d_in[15];
  const float* bl_out  = (const float*)d_in[16];
  const float* w0i_out = (const float*)d_in[17];
  const float* Wlin = (const float*)d_in[18];
  const float* blin = (const float*)d_in[19];

  float* ws      = (float*)d_ws;
  float* efn_in  = ws;
  float* efn_out = efn_in + (size_t)T_INc * EF_W;
  float* flat_in = efn_out + (size_t)T_OUTc * EF_W;
  float* pred    = flat_in + (size_t)BBc * LIN_I;

  const size_t shmem = 65536 * sizeof(u16);   // 131072 B

  (void)hipFuncSetAttribute(reinterpret_cast<const void*>(&eigen_mfma<T_INc>),
                            hipFuncAttributeMaxDynamicSharedMemorySize, (int)shmem);
  (void)hipFuncSetAttribute(reinterpret_cast<const void*>(&eigen_mfma<T_OUTc>),
                            hipFuncAttributeMaxDynamicSharedMemorySize, (int)shmem);

  eigen_mfma<T_INc><<<dim3((T_INc / 64) * E_TOT), dim3(256), shmem, stream>>>(
      W0_in, b0_in, Wh_in, bh_in, Wl_in, bl_in, w0i_in, efn_in);
  eigen_mfma<T_OUTc><<<dim3((T_OUTc / 64) * E_TOT), dim3(256), shmem, stream>>>(
      W0_out, b0_out, Wh_out, bh_out, Wl_out, bl_out, w0i_out, efn_out);

  normalize_kernel<<<dim3(T_INc),  dim3(64), 0, stream>>>(efn_in);
  normalize_kernel<<<dim3(T_OUTc), dim3(64), 0, stream>>>(efn_out);

  coeffs_kernel<<<dim3(NB1, BBc), dim3(64), 0, stream>>>(x_enc, x_mark_enc, efn_in, flat_in);
  linear_kernel<<<dim3(NB1, BBc), dim3(64), 0, stream>>>(flat_in, Wlin, blin, pred);
  recon_kernel<<<dim3(T_OUTc / 4, BBc), dim3(256), 0, stream>>>(pred, efn_out, (float*)d_out);
}

// Round 4
// 422.023 us; speedup vs baseline: 5.2161x; 2.1699x over previous
//
#include <hip/hip_runtime.h>
#include <hip/hip_bf16.h>
#include <math.h>

// SIREN eigenfunction banks + small linear head.
// Hidden layers on MFMA bf16 (hi-only), fast hw sin, W pre-converted to
// swizzled bf16 in workspace by a prep kernel (fallback: in-kernel convert).

typedef short  bf16x8 __attribute__((ext_vector_type(8)));
typedef float  f32x4  __attribute__((ext_vector_type(4)));
typedef unsigned short u16;
typedef u16    u16x8  __attribute__((ext_vector_type(8)));

constexpr int DD    = 128;
constexpr int E_TOT = 1024;
constexpr int T_INc = 512;
constexpr int T_OUTc= 256;
constexpr int BBc   = 32;
constexpr int CCc   = 64;
constexpr int NB1   = 17;
constexpr int EF_W  = NB1 * CCc;     // 1088
constexpr int LIN_I = EF_W + 4;      // 1092
constexpr int LIN_O = EF_W;          // 1088

// bf16 RNE round + exact widen
__device__ __forceinline__ u16 f2b(float f) {
  unsigned u = __builtin_bit_cast(unsigned, f);
  unsigned r = (u + 0x7FFFu + ((u >> 16) & 1u)) >> 16;
  return (u16)r;
}
__device__ __forceinline__ float b2f(u16 u) {
  unsigned v = ((unsigned)u) << 16;
  return __builtin_bit_cast(float, v);
}

// XOR-swizzled element index into a row-major [rows][128] u16 LDS plane.
// byte = row*256 + col*2 ; byte ^= (row&7)<<4  (preserves 16B chunks)
__device__ __forceinline__ int swz(int row, int col) {
  return row * DD + ((((col << 1) ^ ((row & 7) << 4)) >> 1));
}

// ---------------------------------------------------------------------------
// conv_w: fp32 W (tiles of 128x128, row-major) -> bf16, stored SWIZZLED so the
// eigen kernel stages LDS with plain linear 16B copies.
// grid = nTiles*8 blocks x 256 thr; one 8-elem chunk per thread.
// ---------------------------------------------------------------------------
__global__ __launch_bounds__(256) void conv_w(const float* __restrict__ src,
                                              u16* __restrict__ dst)
{
  const int g    = blockIdx.x * 256 + threadIdx.x;  // chunk id
  const int tile = g >> 11;                         // 2048 chunks per tile
  const int ch   = g & 2047;
  const int o    = ch >> 4;
  const int i    = (ch & 15) * 8;
  const size_t base = (size_t)tile * (DD * DD);
  const float4 v0 = *reinterpret_cast<const float4*>(src + base + o * DD + i);
  const float4 v1 = *reinterpret_cast<const float4*>(src + base + o * DD + i + 4);
  u16x8 p;
  p[0] = f2b(v0.x); p[1] = f2b(v0.y); p[2] = f2b(v0.z); p[3] = f2b(v0.w);
  p[4] = f2b(v1.x); p[5] = f2b(v1.y); p[6] = f2b(v1.z); p[7] = f2b(v1.w);
  *reinterpret_cast<u16x8*>(&dst[base + swz(o, i)]) = p;
}

// ---------------------------------------------------------------------------
// eigen_mfma: block = (e, 64-t tile), 4 waves. LDS (u16): Wbuf[16384] @0,
// xA[8192] @16384, xB[8192] @24576  => 64 KiB => 2 blocks/CU.
// W single-buffered: W1 staged up-front, W2 staged under layer-1 compute.
// ---------------------------------------------------------------------------
template<int T, bool PREW>
__global__ __launch_bounds__(256) void eigen_mfma(
    const float* __restrict__ W0, const float* __restrict__ b0,
    const float* __restrict__ Whf, const u16* __restrict__ Whb,
    const float* __restrict__ bh, const float* __restrict__ Wl,
    const float* __restrict__ bl, const float* __restrict__ w0i,
    float* __restrict__ efn)
{
  constexpr int NT = T / 64;
  extern __shared__ u16 lds[];
  u16* Wbuf = lds;
  u16* xA   = lds + 16384;
  u16* xB   = lds + 24576;

  // XCD-friendly mapping: the NT t-tiles of one e land on one XCD consecutively.
  const int b  = blockIdx.x;
  const int e  = (b & 7) + 8 * ((b >> 3) / NT);
  const int t0 = ((b >> 3) % NT) * 64;

  const int tid  = threadIdx.x;
  const int lane = tid & 63;

  auto stageW = [&](int l) {
    if constexpr (PREW) {
      const u16x8* src =
          reinterpret_cast<const u16x8*>(Whb + ((size_t)l * E_TOT + e) * (DD * DD));
      #pragma unroll
      for (int c = 0; c < 8; ++c)
        *reinterpret_cast<u16x8*>(&Wbuf[(c * 256 + tid) * 8]) = src[c * 256 + tid];
    } else {
      const float* Wg = Whf + ((size_t)l * E_TOT + e) * (DD * DD);
      #pragma unroll
      for (int c = 0; c < 8; ++c) {
        const int ch = c * 256 + tid;
        const int o  = ch >> 4;
        const int i  = (ch & 15) * 8;
        const float4 v0 = *reinterpret_cast<const float4*>(Wg + o * DD + i);
        const float4 v1 = *reinterpret_cast<const float4*>(Wg + o * DD + i + 4);
        u16x8 p;
        p[0] = f2b(v0.x); p[1] = f2b(v0.y); p[2] = f2b(v0.z); p[3] = f2b(v0.w);
        p[4] = f2b(v1.x); p[5] = f2b(v1.y); p[6] = f2b(v1.z); p[7] = f2b(v1.w);
        *reinterpret_cast<u16x8*>(&Wbuf[swz(o, i)]) = p;
      }
    }
  };

  stageW(0);

  // ---- layer 0: xA[t][d] = sin(w0i*(W0[d]*dom + b0[d])) ----
  {
    const int t = tid >> 2;
    const int q = tid & 3;
    const float dom = (float)(t0 + t) * (1.0f / (float)(T - 1));
    const float wi  = w0i[e];
    #pragma unroll
    for (int c = 0; c < 4; ++c) {
      const int d = q * 32 + c * 8;
      const float4 w0v = *reinterpret_cast<const float4*>(W0 + (size_t)e * DD + d);
      const float4 w1v = *reinterpret_cast<const float4*>(W0 + (size_t)e * DD + d + 4);
      const float4 b0v = *reinterpret_cast<const float4*>(b0 + (size_t)e * DD + d);
      const float4 b1v = *reinterpret_cast<const float4*>(b0 + (size_t)e * DD + d + 4);
      u16x8 p;
      p[0] = f2b(__sinf(wi * (w0v.x * dom + b0v.x)));
      p[1] = f2b(__sinf(wi * (w0v.y * dom + b0v.y)));
      p[2] = f2b(__sinf(wi * (w0v.z * dom + b0v.z)));
      p[3] = f2b(__sinf(wi * (w0v.w * dom + b0v.w)));
      p[4] = f2b(__sinf(wi * (w1v.x * dom + b1v.x)));
      p[5] = f2b(__sinf(wi * (w1v.y * dom + b1v.y)));
      p[6] = f2b(__sinf(wi * (w1v.z * dom + b1v.z)));
      p[7] = f2b(__sinf(wi * (w1v.w * dom + b1v.w)));
      *reinterpret_cast<u16x8*>(&xA[swz(t, d)]) = p;
    }
  }
  __syncthreads();

  // ---- hidden layers (MFMA, bf16 hi-only) ----
  const int wv = tid >> 6;        // wave 0..3
  const int wt = wv >> 1;         // t-group: rows wt*32..+32
  const int wo = wv & 1;          // o-group: cols wo*64..+64
  const int lm = lane & 15;
  const int lg = lane >> 4;

  for (int l = 0; l < 2; ++l) {
    const u16* xin = (l == 0) ? xA : xB;
    u16*       xout= (l == 0) ? xB : xA;

    // read all W fragments up-front (frees Wbuf for restage)
    bf16x8 wf[4][4];
    #pragma unroll
    for (int kk = 0; kk < 4; ++kk)
      #pragma unroll
      for (int n = 0; n < 4; ++n)
        wf[kk][n] = *reinterpret_cast<const bf16x8*>(
            &Wbuf[swz(wo * 64 + n * 16 + lm, kk * 32 + lg * 8)]);

    __syncthreads();              // all waves done reading Wbuf
    if (l == 0) stageW(1);        // overwrite Wbuf under layer-1 compute

    float bhv[4];
    #pragma unroll
    for (int n = 0; n < 4; ++n)
      bhv[n] = bh[((size_t)l * E_TOT + e) * DD + wo * 64 + n * 16 + lm];

    f32x4 acc[2][4];
    #pragma unroll
    for (int m = 0; m < 2; ++m)
      #pragma unroll
      for (int n = 0; n < 4; ++n) acc[m][n] = (f32x4){0.f, 0.f, 0.f, 0.f};

    #pragma unroll
    for (int kk = 0; kk < 4; ++kk) {
      const int kb = kk * 32 + lg * 8;
      bf16x8 xf[2];
      #pragma unroll
      for (int m = 0; m < 2; ++m)
        xf[m] = *reinterpret_cast<const bf16x8*>(
            &xin[swz(wt * 32 + m * 16 + lm, kb)]);
      #pragma unroll
      for (int m = 0; m < 2; ++m)
        #pragma unroll
        for (int n = 0; n < 4; ++n)
          acc[m][n] = __builtin_amdgcn_mfma_f32_16x16x32_bf16(xf[m], wf[kk][n], acc[m][n], 0, 0, 0);
    }

    // activation + write (C/D layout: col = lane&15, row = lg*4 + r)
    #pragma unroll
    for (int m = 0; m < 2; ++m)
      #pragma unroll
      for (int n = 0; n < 4; ++n) {
        const int o = wo * 64 + n * 16 + lm;
        #pragma unroll
        for (int r = 0; r < 4; ++r) {
          const int t = wt * 32 + m * 16 + lg * 4 + r;
          xout[swz(t, o)] = f2b(__sinf(acc[m][n][r] + bhv[n]));
        }
      }
    __syncthreads();
  }

  // ---- final layer: y[t] = Wl[e,:] . x2[:,t] + bl[e]  (x2 in xA) ----
  {
    const int t = tid >> 2;
    const int q = tid & 3;
    float acc = 0.0f;
    #pragma unroll
    for (int c = 0; c < 4; ++c) {
      const int i = q * 32 + c * 8;
      const bf16x8 hv = *reinterpret_cast<const bf16x8*>(&xA[swz(t, i)]);
      #pragma unroll
      for (int j = 0; j < 8; ++j)
        acc += Wl[(size_t)e * DD + i + j] * b2f((u16)hv[j]);
    }
    acc += __shfl_xor(acc, 1);
    acc += __shfl_xor(acc, 2);
    if (q == 0)
      efn[(size_t)(t0 + t) * EF_W + CCc + e] = acc + bl[e];
  }
}

// ---------------------------------------------------------------------------
__global__ void normalize_kernel(float* __restrict__ efn)
{
  const int t = blockIdx.x;
  const int c = threadIdx.x;   // 64
  float* row = efn + (size_t)t * EF_W;
  float v[16];
  float s = 1.0f;
  #pragma unroll
  for (int n = 0; n < 16; ++n) {
    v[n] = row[CCc + n * CCc + c];
    s += v[n] * v[n];
  }
  const float inv = 1.0f / sqrtf(s);
  row[c] = inv;
  #pragma unroll
  for (int n = 0; n < 16; ++n)
    row[CCc + n * CCc + c] = v[n] * inv;
}

__global__ void coeffs_kernel(const float* __restrict__ x_enc,
                              const float* __restrict__ x_mark_enc,
                              const float* __restrict__ efn_in,
                              float* __restrict__ flat_in)
{
  const int n = blockIdx.x;   // 17
  const int b = blockIdx.y;   // 32
  const int c = threadIdx.x;  // 64
  float acc = 0.0f;
  for (int t = 0; t < T_INc; ++t)
    acc += x_enc[((size_t)b * T_INc + t) * CCc + c]
         * efn_in[(size_t)t * EF_W + n * CCc + c];
  flat_in[b * LIN_I + n * CCc + c] = acc;
  if (n == 0 && c < 4)
    flat_in[b * LIN_I + EF_W + c] =
        x_mark_enc[((size_t)b * T_INc + (T_INc - 1)) * 4 + c];
}

__global__ void linear_kernel(const float* __restrict__ flat_in,
                              const float* __restrict__ Wlin,
                              const float* __restrict__ blin,
                              float* __restrict__ pred)
{
  const int o = blockIdx.x * 64 + threadIdx.x;  // 1088
  const int b = blockIdx.y;                     // 32
  const float* w  = Wlin + (size_t)o * LIN_I;
  const float* xi = flat_in + b * LIN_I;
  float acc = blin[o];
  for (int j = 0; j < LIN_I; ++j) acc += w[j] * xi[j];
  pred[b * LIN_O + o] = acc;
}

__global__ void recon_kernel(const float* __restrict__ pred,
                             const float* __restrict__ efn_out,
                             float* __restrict__ out)
{
  const int b = blockIdx.y;
  const int t = blockIdx.x * 4 + (threadIdx.x >> 6);
  const int c = threadIdx.x & 63;
  float acc = 0.0f;
  #pragma unroll
  for (int n = 0; n < NB1; ++n)
    acc += pred[b * LIN_O + n * CCc + c]
         * efn_out[(size_t)t * EF_W + n * CCc + c];
  out[((size_t)b * T_OUTc + t) * CCc + c] = acc;
}

// ---------------------------------------------------------------------------
extern "C" void kernel_launch(void* const* d_in, const int* in_sizes, int n_in,
                              void* d_out, int out_size, void* d_ws, size_t ws_size,
                              hipStream_t stream)
{
  const float* x_enc      = (const float*)d_in[0];
  const float* x_mark_enc = (const float*)d_in[1];
  const float* W0_in  = (const float*)d_in[4];
  const float* b0_in  = (const float*)d_in[5];
  const float* Wh_in  = (const float*)d_in[6];
  const float* bh_in  = (const float*)d_in[7];
  const float* Wl_in  = (const float*)d_in[8];
  const float* bl_in  = (const float*)d_in[9];
  const float* w0i_in = (const float*)d_in[10];
  const float* W0_out  = (const float*)d_in[11];
  const float* b0_out  = (const float*)d_in[12];
  const float* Wh_out  = (const float*)d_in[13];
  const float* bh_out  = (const float*)d_in[14];
  const float* Wl_out  = (const float*)d_in[15];
  const float* bl_out  = (const float*)d_in[16];
  const float* w0i_out = (const float*)d_in[17];
  const float* Wlin = (const float*)d_in[18];
  const float* blin = (const float*)d_in[19];

  const size_t wElems = (size_t)2 * E_TOT * DD * DD;      // per bank (u16 elems)
  const size_t efnElems = (size_t)T_INc * EF_W + (size_t)T_OUTc * EF_W
                        + (size_t)BBc * LIN_I + (size_t)BBc * LIN_O;
  const size_t needBytes = 2 * wElems * sizeof(u16) + efnElems * sizeof(float);
  const bool prew = (ws_size >= needBytes);

  u16* wsWin  = (u16*)d_ws;
  u16* wsWout = wsWin + wElems;
  float* efn_in = prew ? (float*)(wsWout + wElems) : (float*)d_ws;
  float* efn_out = efn_in + (size_t)T_INc * EF_W;
  float* flat_in = efn_out + (size_t)T_OUTc * EF_W;
  float* pred    = flat_in + (size_t)BBc * LIN_I;

  const size_t shmem = 32768 * sizeof(u16);   // 65536 B -> 2 blocks/CU

  (void)hipFuncSetAttribute(reinterpret_cast<const void*>(&eigen_mfma<T_INc, true>),
                            hipFuncAttributeMaxDynamicSharedMemorySize, (int)shmem);
  (void)hipFuncSetAttribute(reinterpret_cast<const void*>(&eigen_mfma<T_OUTc, true>),
                            hipFuncAttributeMaxDynamicSharedMemorySize, (int)shmem);
  (void)hipFuncSetAttribute(reinterpret_cast<const void*>(&eigen_mfma<T_INc, false>),
                            hipFuncAttributeMaxDynamicSharedMemorySize, (int)shmem);
  (void)hipFuncSetAttribute(reinterpret_cast<const void*>(&eigen_mfma<T_OUTc, false>),
                            hipFuncAttributeMaxDynamicSharedMemorySize, (int)shmem);

  if (prew) {
    conv_w<<<dim3(2 * E_TOT * 8), dim3(256), 0, stream>>>(Wh_in,  wsWin);
    conv_w<<<dim3(2 * E_TOT * 8), dim3(256), 0, stream>>>(Wh_out, wsWout);
    eigen_mfma<T_INc, true><<<dim3((T_INc / 64) * E_TOT), dim3(256), shmem, stream>>>(
        W0_in, b0_in, nullptr, wsWin, bh_in, Wl_in, bl_in, w0i_in, efn_in);
    eigen_mfma<T_OUTc, true><<<dim3((T_OUTc / 64) * E_TOT), dim3(256), shmem, stream>>>(
        W0_out, b0_out, nullptr, wsWout, bh_out, Wl_out, bl_out, w0i_out, efn_out);
  } else {
    eigen_mfma<T_INc, false><<<dim3((T_INc / 64) * E_TOT), dim3(256), shmem, stream>>>(
        W0_in, b0_in, Wh_in, nullptr, bh_in, Wl_in, bl_in, w0i_in, efn_in);
    eigen_mfma<T_OUTc, false><<<dim3((T_OUTc / 64) * E_TOT), dim3(256), shmem, stream>>>(
        W0_out, b0_out, Wh_out, nullptr, bh_out, Wl_out, bl_out, w0i_out, efn_out);
  }

  normalize_kernel<<<dim3(T_INc),  dim3(64), 0, stream>>>(efn_in);
  normalize_kernel<<<dim3(T_OUTc), dim3(64), 0, stream>>>(efn_out);

  coeffs_kernel<<<dim3(NB1, BBc), dim3(64), 0, stream>>>(x_enc, x_mark_enc, efn_in, flat_in);
  linear_kernel<<<dim3(NB1, BBc), dim3(64), 0, stream>>>(flat_in, Wlin, blin, pred);
  recon_kernel<<<dim3(T_OUTc / 4, BBc), dim3(256), 0, stream>>>(pred, efn_out, (float*)d_out);
}

// Round 6
// 327.561 us; speedup vs baseline: 6.7203x; 1.2884x over previous
//
#include <hip/hip_runtime.h>
#include <hip/hip_bf16.h>
#include <math.h>

// SIREN eigenfunction banks + small linear head.
// eigen: round-3-proven MFMA structure (A=x LDS, B=W LDS, XOR-swizzled),
// upgraded to 512 thr / 8 waves, 4 barriers, W2 reg-prefetch, 64KB LDS.

typedef short  bf16x8 __attribute__((ext_vector_type(8)));
typedef float  f32x4  __attribute__((ext_vector_type(4)));
typedef unsigned short u16;
typedef u16    u16x8  __attribute__((ext_vector_type(8)));

constexpr int DD    = 128;
constexpr int E_TOT = 1024;
constexpr int T_INc = 512;
constexpr int T_OUTc= 256;
constexpr int BBc   = 32;
constexpr int CCc   = 64;
constexpr int NB1   = 17;
constexpr int EF_W  = NB1 * CCc;     // 1088
constexpr int LIN_I = EF_W + 4;      // 1092
constexpr int LIN_O = EF_W;          // 1088

__device__ __forceinline__ u16 f2b(float f) {          // bf16 RNE
  unsigned u = __builtin_bit_cast(unsigned, f);
  return (u16)((u + 0x7FFFu + ((u >> 16) & 1u)) >> 16);
}
__device__ __forceinline__ float b2f(u16 u) {
  unsigned v = ((unsigned)u) << 16;
  return __builtin_bit_cast(float, v);
}

// XOR-swizzled element index into a row-major [rows][128] u16 LDS plane.
// byte = row*256 + ((col*2) ^ ((row&7)<<4))   (proven in rounds 3/4-pass)
__device__ __forceinline__ int swz(int row, int col) {
  return row * DD + ((((col << 1) ^ ((row & 7) << 4)) >> 1));
}

// ---------------------------------------------------------------------------
// eigen_mfma: block = (e, 64-t tile), 512 thr / 8 waves (wt 0..1 x wo 0..3),
// each wave 32t x 32o. LDS (u16): Wbuf[16384] @0, xA @16384, xB @24576 = 64KB.
// Barriers: (1) W1+xA ready, (2) W1/xA reads done, (3) W2+xB ready, (4) x2.
// ---------------------------------------------------------------------------
template<int T>
__global__ __launch_bounds__(512, 4) void eigen_mfma(
    const float* __restrict__ W0, const float* __restrict__ b0,
    const float* __restrict__ Wh, const float* __restrict__ bh,
    const float* __restrict__ Wl, const float* __restrict__ bl,
    const float* __restrict__ w0i, float* __restrict__ efn)
{
  constexpr int NT = T / 64;
  extern __shared__ u16 lds[];
  u16* Wbuf = lds;
  u16* xA   = lds + 16384;
  u16* xB   = lds + 24576;

  // XCD-grouped mapping (proven round 3): t-tiles of one e stay on one XCD.
  const int b  = blockIdx.x;
  const int e  = (b & 7) + 8 * ((b >> 3) / NT);
  const int t0 = ((b >> 3) % NT) * 64;

  const int tid  = threadIdx.x;
  const int lane = tid & 63;
  const int wv   = tid >> 6;      // wave 0..7
  const int wt   = wv >> 2;       // t-group: rows wt*32..+32
  const int wo   = wv & 3;        // o-group: cols wo*32..+32
  const int lm   = lane & 15;
  const int lg   = lane >> 4;

  // ---- stage W1 -> LDS (fp32 -> bf16 in flight, swizzled) ----
  {
    const float* Wg = Wh + (size_t)e * (DD * DD);   // layer 0 of Wh
    #pragma unroll
    for (int c = 0; c < 4; ++c) {
      const int ch = c * 512 + tid;        // 2048 chunks of 8 elems
      const int o  = ch >> 4;
      const int i  = (ch & 15) * 8;
      const float4 v0 = *(const float4*)(Wg + o * DD + i);
      const float4 v1 = *(const float4*)(Wg + o * DD + i + 4);
      u16x8 p;
      p[0] = f2b(v0.x); p[1] = f2b(v0.y); p[2] = f2b(v0.z); p[3] = f2b(v0.w);
      p[4] = f2b(v1.x); p[5] = f2b(v1.y); p[6] = f2b(v1.z); p[7] = f2b(v1.w);
      *(u16x8*)&Wbuf[swz(o, i)] = p;
    }
  }

  // ---- prefetch W2 (fp32) into registers; ds_write happens after sync(2) ----
  float4 pre[8];
  {
    const float* Wg = Wh + ((size_t)E_TOT + e) * (DD * DD);
    #pragma unroll
    for (int c = 0; c < 4; ++c) {
      const int ch = c * 512 + tid;
      const int o  = ch >> 4;
      const int i  = (ch & 15) * 8;
      pre[c * 2 + 0] = *(const float4*)(Wg + o * DD + i);
      pre[c * 2 + 1] = *(const float4*)(Wg + o * DD + i + 4);
    }
  }

  // ---- layer 0: xA[t][d] = sin(w0i*(W0[d]*dom + b0[d])) ----
  {
    const int t = tid >> 3;          // 0..63
    const int q = tid & 7;           // d = q*16 .. +15
    const float dom = (float)(t0 + t) * (1.0f / (float)(T - 1));
    const float wi  = w0i[e];
    #pragma unroll
    for (int c = 0; c < 2; ++c) {
      const int d = q * 16 + c * 8;
      const float4 wA = *(const float4*)(W0 + (size_t)e * DD + d);
      const float4 wB = *(const float4*)(W0 + (size_t)e * DD + d + 4);
      const float4 bA = *(const float4*)(b0 + (size_t)e * DD + d);
      const float4 bB = *(const float4*)(b0 + (size_t)e * DD + d + 4);
      u16x8 p;
      p[0] = f2b(__sinf(wi * (wA.x * dom + bA.x)));
      p[1] = f2b(__sinf(wi * (wA.y * dom + bA.y)));
      p[2] = f2b(__sinf(wi * (wA.z * dom + bA.z)));
      p[3] = f2b(__sinf(wi * (wA.w * dom + bA.w)));
      p[4] = f2b(__sinf(wi * (wB.x * dom + bB.x)));
      p[5] = f2b(__sinf(wi * (wB.y * dom + bB.y)));
      p[6] = f2b(__sinf(wi * (wB.z * dom + bB.z)));
      p[7] = f2b(__sinf(wi * (wB.w * dom + bB.w)));
      *(u16x8*)&xA[swz(t, d)] = p;
    }
  }
  __syncthreads();   // (1) W1 + xA ready

  f32x4 acc[2][2];

  // ---- hidden layer 1: acc = xA . W1^T ----
  #pragma unroll
  for (int m = 0; m < 2; ++m)
    #pragma unroll
    for (int n = 0; n < 2; ++n) acc[m][n] = (f32x4){0.f, 0.f, 0.f, 0.f};
  #pragma unroll
  for (int kk = 0; kk < 4; ++kk) {
    const int kb = kk * 32 + lg * 8;
    bf16x8 ah[2], bw[2];
    #pragma unroll
    for (int m = 0; m < 2; ++m)
      ah[m] = *(const bf16x8*)&xA[swz(wt * 32 + m * 16 + lm, kb)];
    #pragma unroll
    for (int n = 0; n < 2; ++n)
      bw[n] = *(const bf16x8*)&Wbuf[swz(wo * 32 + n * 16 + lm, kb)];
    #pragma unroll
    for (int m = 0; m < 2; ++m)
      #pragma unroll
      for (int n = 0; n < 2; ++n)
        acc[m][n] = __builtin_amdgcn_mfma_f32_16x16x32_bf16(ah[m], bw[n], acc[m][n], 0, 0, 0);
  }
  __syncthreads();   // (2) all waves done reading W1 (and xA)

  // ---- write W2 into Wbuf (from prefetched regs) ----
  {
    #pragma unroll
    for (int c = 0; c < 4; ++c) {
      const int ch = c * 512 + tid;
      const int o  = ch >> 4;
      const int i  = (ch & 15) * 8;
      const float4 v0 = pre[c * 2 + 0];
      const float4 v1 = pre[c * 2 + 1];
      u16x8 p;
      p[0] = f2b(v0.x); p[1] = f2b(v0.y); p[2] = f2b(v0.z); p[3] = f2b(v0.w);
      p[4] = f2b(v1.x); p[5] = f2b(v1.y); p[6] = f2b(v1.z); p[7] = f2b(v1.w);
      *(u16x8*)&Wbuf[swz(o, i)] = p;
    }
  }
  // ---- act1 -> xB (C/D layout: col=lane&15 -> o, row=lg*4+r -> t) ----
  #pragma unroll
  for (int m = 0; m < 2; ++m)
    #pragma unroll
    for (int n = 0; n < 2; ++n) {
      const int o = wo * 32 + n * 16 + lm;
      const float bhv = bh[(size_t)e * DD + o];
      #pragma unroll
      for (int r = 0; r < 4; ++r) {
        const int t = wt * 32 + m * 16 + lg * 4 + r;
        xB[swz(t, o)] = f2b(__sinf(acc[m][n][r] + bhv));
      }
    }
  __syncthreads();   // (3) W2 + xB ready

  // ---- hidden layer 2: acc = xB . W2^T ----
  #pragma unroll
  for (int m = 0; m < 2; ++m)
    #pragma unroll
    for (int n = 0; n < 2; ++n) acc[m][n] = (f32x4){0.f, 0.f, 0.f, 0.f};
  #pragma unroll
  for (int kk = 0; kk < 4; ++kk) {
    const int kb = kk * 32 + lg * 8;
    bf16x8 ah[2], bw[2];
    #pragma unroll
    for (int m = 0; m < 2; ++m)
      ah[m] = *(const bf16x8*)&xB[swz(wt * 32 + m * 16 + lm, kb)];
    #pragma unroll
    for (int n = 0; n < 2; ++n)
      bw[n] = *(const bf16x8*)&Wbuf[swz(wo * 32 + n * 16 + lm, kb)];
    #pragma unroll
    for (int m = 0; m < 2; ++m)
      #pragma unroll
      for (int n = 0; n < 2; ++n)
        acc[m][n] = __builtin_amdgcn_mfma_f32_16x16x32_bf16(ah[m], bw[n], acc[m][n], 0, 0, 0);
  }
  // ---- act2 -> xA (xA reads finished at sync(2)) ----
  #pragma unroll
  for (int m = 0; m < 2; ++m)
    #pragma unroll
    for (int n = 0; n < 2; ++n) {
      const int o = wo * 32 + n * 16 + lm;
      const float bhv = bh[(size_t)(E_TOT + e) * DD + o];
      #pragma unroll
      for (int r = 0; r < 4; ++r) {
        const int t = wt * 32 + m * 16 + lg * 4 + r;
        xA[swz(t, o)] = f2b(__sinf(acc[m][n][r] + bhv));
      }
    }
  __syncthreads();   // (4) x2 ready

  // ---- final layer: y[t] = Wl[e,:] . x2[t,:] + bl[e] ----
  {
    const int t = tid >> 3;          // 0..63
    const int q = tid & 7;           // d-chunk q*16..+15
    const int i = q * 16;
    float a = 0.0f;
    const bf16x8 h0 = *(const bf16x8*)&xA[swz(t, i)];
    const bf16x8 h1 = *(const bf16x8*)&xA[swz(t, i + 8)];
    #pragma unroll
    for (int j = 0; j < 8; ++j) {
      a += Wl[(size_t)e * DD + i + j]     * b2f((u16)h0[j]);
      a += Wl[(size_t)e * DD + i + 8 + j] * b2f((u16)h1[j]);
    }
    a += __shfl_xor(a, 1);
    a += __shfl_xor(a, 2);
    a += __shfl_xor(a, 4);
    if (q == 0)
      efn[(size_t)(t0 + t) * EF_W + CCc + e] = a + bl[e];
  }
}

// ---------------------------------------------------------------------------
__global__ void normalize_kernel(float* __restrict__ efn)
{
  const int t = blockIdx.x;
  const int c = threadIdx.x;   // 64
  float* row = efn + (size_t)t * EF_W;
  float v[16];
  float s = 1.0f;
  #pragma unroll
  for (int n = 0; n < 16; ++n) {
    v[n] = row[CCc + n * CCc + c];
    s += v[n] * v[n];
  }
  const float inv = 1.0f / sqrtf(s);
  row[c] = inv;
  #pragma unroll
  for (int n = 0; n < 16; ++n)
    row[CCc + n * CCc + c] = v[n] * inv;
}

// coeffs: block (n, b), 256 thr = 64 c x 4 t-chunks, LDS reduce.
__global__ __launch_bounds__(256) void coeffs_kernel(
    const float* __restrict__ x_enc, const float* __restrict__ x_mark_enc,
    const float* __restrict__ efn_in, float* __restrict__ flat_in)
{
  const int n  = blockIdx.x;   // 17
  const int b  = blockIdx.y;   // 32
  const int c  = threadIdx.x & 63;
  const int ch = threadIdx.x >> 6;   // 0..3
  __shared__ float red[4][64];
  float acc = 0.0f;
  #pragma unroll 4
  for (int t = ch * 128; t < ch * 128 + 128; ++t)
    acc += x_enc[((size_t)b * T_INc + t) * CCc + c]
         * efn_in[(size_t)t * EF_W + n * CCc + c];
  red[ch][c] = acc;
  __syncthreads();
  if (ch == 0) {
    acc += red[1][c] + red[2][c] + red[3][c];
    flat_in[b * LIN_I + n * CCc + c] = acc;
    if (n == 0 && c < 4)
      flat_in[b * LIN_I + EF_W + c] =
          x_mark_enc[((size_t)b * T_INc + (T_INc - 1)) * 4 + c];
  }
}

// Wlin transpose (for coalesced GEMV)
__global__ __launch_bounds__(256) void transpose_lin(const float* __restrict__ W,
                                                     float* __restrict__ Wt)
{
  __shared__ float tile[32][33];
  const int j0 = blockIdx.x * 32;
  const int o0 = blockIdx.y * 32;
  const int tx = threadIdx.x & 31, ty = threadIdx.x >> 5;  // ty 0..7
  #pragma unroll
  for (int r = 0; r < 32; r += 8) {
    const int o = o0 + ty + r, j = j0 + tx;
    tile[ty + r][tx] = (o < LIN_O && j < LIN_I) ? W[(size_t)o * LIN_I + j] : 0.f;
  }
  __syncthreads();
  #pragma unroll
  for (int r = 0; r < 32; r += 8) {
    const int j = j0 + ty + r, o = o0 + tx;
    if (j < LIN_I && o < LIN_O) Wt[(size_t)j * LIN_O + o] = tile[tx][ty + r];
  }
}

// linear (transposed W): block (o-tile, b), 256 thr = 64 o x 4 j-chunks.
__global__ __launch_bounds__(256) void linear_t_kernel(
    const float* __restrict__ flat_in, const float* __restrict__ Wt,
    const float* __restrict__ blin, float* __restrict__ pred)
{
  const int og = blockIdx.x;   // 17
  const int b  = blockIdx.y;   // 32
  const int c  = threadIdx.x & 63;
  const int ch = threadIdx.x >> 6;
  const int o  = og * 64 + c;
  __shared__ float red[4][64];
  const float* xi = flat_in + b * LIN_I;
  float acc = 0.0f;
  #pragma unroll 4
  for (int j = ch * 273; j < ch * 273 + 273; ++j)
    acc += Wt[(size_t)j * LIN_O + o] * xi[j];
  red[ch][c] = acc;
  __syncthreads();
  if (ch == 0)
    pred[b * LIN_O + o] = acc + red[1][c] + red[2][c] + red[3][c] + blin[o];
}

// fallback row-major linear (if ws too small for Wt)
__global__ void linear_row_kernel(const float* __restrict__ flat_in,
                                  const float* __restrict__ Wlin,
                                  const float* __restrict__ blin,
                                  float* __restrict__ pred)
{
  const int o = blockIdx.x * 64 + threadIdx.x;
  const int b = blockIdx.y;
  const float* w  = Wlin + (size_t)o * LIN_I;
  const float* xi = flat_in + b * LIN_I;
  float acc = blin[o];
  for (int j = 0; j < LIN_I; ++j) acc += w[j] * xi[j];
  pred[b * LIN_O + o] = acc;
}

__global__ void recon_kernel(const float* __restrict__ pred,
                             const float* __restrict__ efn_out,
                             float* __restrict__ out)
{
  const int b = blockIdx.y;
  const int t = blockIdx.x * 4 + (threadIdx.x >> 6);
  const int c = threadIdx.x & 63;
  float acc = 0.0f;
  #pragma unroll
  for (int n = 0; n < NB1; ++n)
    acc += pred[b * LIN_O + n * CCc + c]
         * efn_out[(size_t)t * EF_W + n * CCc + c];
  out[((size_t)b * T_OUTc + t) * CCc + c] = acc;
}

// ---------------------------------------------------------------------------
extern "C" void kernel_launch(void* const* d_in, const int* in_sizes, int n_in,
                              void* d_out, int out_size, void* d_ws, size_t ws_size,
                              hipStream_t stream)
{
  const float* x_enc      = (const float*)d_in[0];
  const float* x_mark_enc = (const float*)d_in[1];
  const float* W0_in  = (const float*)d_in[4];
  const float* b0_in  = (const float*)d_in[5];
  const float* Wh_in  = (const float*)d_in[6];
  const float* bh_in  = (const float*)d_in[7];
  const float* Wl_in  = (const float*)d_in[8];
  const float* bl_in  = (const float*)d_in[9];
  const float* w0i_in = (const float*)d_in[10];
  const float* W0_out  = (const float*)d_in[11];
  const float* b0_out  = (const float*)d_in[12];
  const float* Wh_out  = (const float*)d_in[13];
  const float* bh_out  = (const float*)d_in[14];
  const float* Wl_out  = (const float*)d_in[15];
  const float* bl_out  = (const float*)d_in[16];
  const float* w0i_out = (const float*)d_in[17];
  const float* Wlin = (const float*)d_in[18];
  const float* blin = (const float*)d_in[19];

  float* ws      = (float*)d_ws;
  float* efn_in  = ws;                                   // 512*1088
  float* efn_out = efn_in + (size_t)T_INc * EF_W;        // 256*1088
  float* flat_in = efn_out + (size_t)T_OUTc * EF_W;      // 32*1092
  float* pred    = flat_in + (size_t)BBc * LIN_I;        // 32*1088
  float* Wt      = pred + (size_t)BBc * LIN_O;           // 1092*1088
  const size_t needWt = ((size_t)(Wt - ws) + (size_t)LIN_I * LIN_O) * sizeof(float);
  const bool useWt = (ws_size >= needWt);

  const int shmem = 32768 * (int)sizeof(u16);   // 65536 B -> 2 blocks/CU

  (void)hipFuncSetAttribute(reinterpret_cast<const void*>(&eigen_mfma<T_INc>),
                            hipFuncAttributeMaxDynamicSharedMemorySize, shmem);
  (void)hipFuncSetAttribute(reinterpret_cast<const void*>(&eigen_mfma<T_OUTc>),
                            hipFuncAttributeMaxDynamicSharedMemorySize, shmem);

  eigen_mfma<T_INc><<<dim3((T_INc / 64) * E_TOT), dim3(512), shmem, stream>>>(
      W0_in, b0_in, Wh_in, bh_in, Wl_in, bl_in, w0i_in, efn_in);
  eigen_mfma<T_OUTc><<<dim3((T_OUTc / 64) * E_TOT), dim3(512), shmem, stream>>>(
      W0_out, b0_out, Wh_out, bh_out, Wl_out, bl_out, w0i_out, efn_out);

  normalize_kernel<<<dim3(T_INc),  dim3(64), 0, stream>>>(efn_in);
  normalize_kernel<<<dim3(T_OUTc), dim3(64), 0, stream>>>(efn_out);

  coeffs_kernel<<<dim3(NB1, BBc), dim3(256), 0, stream>>>(x_enc, x_mark_enc, efn_in, flat_in);

  if (useWt) {
    transpose_lin<<<dim3((LIN_I + 31) / 32, (LIN_O + 31) / 32), dim3(256), 0, stream>>>(Wlin, Wt);
    linear_t_kernel<<<dim3(NB1, BBc), dim3(256), 0, stream>>>(flat_in, Wt, blin, pred);
  } else {
    linear_row_kernel<<<dim3(NB1, BBc), dim3(64), 0, stream>>>(flat_in, Wlin, blin, pred);
  }

  recon_kernel<<<dim3(T_OUTc / 4, BBc), dim3(256), 0, stream>>>(pred, efn_out, (float*)d_out);
}

// Round 8
// 246.484 us; speedup vs baseline: 8.9308x; 1.3289x over previous
//
#include <hip/hip_runtime.h>
#include <hip/hip_bf16.h>
#include <math.h>

// SIREN eigenfunction banks + small linear head.
// eigen: persistent-e kernel (one block per e, 512 thr / 8 waves, W fragments
// for both hidden layers in registers, ping-pong x planes, 3 barriers/iter).
// ALL bf16 conversion via proven f2b (NO v_cvt_pk_bf16_f32 — prime suspect in
// rounds 4/7 failures: operand->half order unverified).

typedef short  bf16x8 __attribute__((ext_vector_type(8)));
typedef float  f32x4  __attribute__((ext_vector_type(4)));
typedef unsigned short u16;
typedef u16    u16x8  __attribute__((ext_vector_type(8)));

constexpr int DD    = 128;
constexpr int E_TOT = 1024;
constexpr int T_INc = 512;
constexpr int T_OUTc= 256;
constexpr int BBc   = 32;
constexpr int CCc   = 64;
constexpr int NB1   = 17;
constexpr int EF_W  = NB1 * CCc;     // 1088
constexpr int LIN_I = EF_W + 4;      // 1092
constexpr int LIN_O = EF_W;          // 1088

__device__ __forceinline__ u16 f2b(float f) {          // bf16 RNE (proven)
  unsigned u = __builtin_bit_cast(unsigned, f);
  return (u16)((u + 0x7FFFu + ((u >> 16) & 1u)) >> 16);
}
__device__ __forceinline__ float b2f(u16 u) {
  unsigned v = ((unsigned)u) << 16;
  return __builtin_bit_cast(float, v);
}

// XOR-swizzled element index into a row-major [rows][128] u16 LDS plane.
// byte = row*256 + ((col*2) ^ ((row&7)<<4))   (proven rounds 3/6)
__device__ __forceinline__ int swz(int row, int col) {
  return row * DD + ((((col << 1) ^ ((row & 7) << 4)) >> 1));
}

// ---------------------------------------------------------------------------
// eigen_persist: grid = E_TOT. 8 waves = (wt 0..1) x (wo 0..3), wave tile
// 32t x 32o per 64-t iteration. W frags in regs: wfrag[layer][kk][n].
// ---------------------------------------------------------------------------
template<int T>
__global__ __launch_bounds__(512, 4) void eigen_persist(
    const float* __restrict__ W0, const float* __restrict__ b0,
    const float* __restrict__ Wh, const float* __restrict__ bh,
    const float* __restrict__ Wl, const float* __restrict__ bl,
    const float* __restrict__ w0i, float* __restrict__ efn)
{
  constexpr int NIT = T / 64;
  __shared__ u16 xP[2][8192];          // two 64x128 bf16 planes (swizzled)
  __shared__ float w0s[128], b0s[128], wls[128];

  const int e    = blockIdx.x;
  const int tid  = threadIdx.x;
  const int lane = tid & 63;
  const int wv   = tid >> 6;      // wave 0..7
  const int wt   = wv >> 2;       // t-group: rows wt*32..+32
  const int wo   = wv & 3;        // o-group: cols wo*32..+32
  const int lm   = lane & 15;
  const int lg   = lane >> 4;

  // ---- stage small per-e vectors to LDS ----
  if (tid < 128)       w0s[tid]       = W0[(size_t)e * DD + tid];
  else if (tid < 256)  b0s[tid - 128] = b0[(size_t)e * DD + tid - 128];
  else if (tid < 384)  wls[tid - 256] = Wl[(size_t)e * DD + tid - 256];
  const float wi  = w0i[e];
  const float blv = bl[e];

  // ---- bias preload (per-lane o = wo*32 + n*16 + lm) ----
  float bhv[2][2];
  #pragma unroll
  for (int l = 0; l < 2; ++l)
    #pragma unroll
    for (int n = 0; n < 2; ++n)
      bhv[l][n] = bh[((size_t)l * E_TOT + e) * DD + wo * 32 + n * 16 + lm];

  // ---- W fragments: global fp32 -> bf16 regs (held across all iterations).
  // B-frag (proven round 6): lane(lm,lg) holds
  //   W[o = wo*32+n*16+lm][k = kk*32+lg*8 .. +7]
  bf16x8 wfrag[2][4][2];
  #pragma unroll
  for (int l = 0; l < 2; ++l) {
    const float* Wg = Wh + ((size_t)l * E_TOT + e) * (DD * DD);
    #pragma unroll
    for (int kk = 0; kk < 4; ++kk)
      #pragma unroll
      for (int n = 0; n < 2; ++n) {
        const float* p = Wg + (wo * 32 + n * 16 + lm) * DD + kk * 32 + lg * 8;
        const float4 a = *(const float4*)p;
        const float4 c = *(const float4*)(p + 4);
        u16x8 u;
        u[0] = f2b(a.x); u[1] = f2b(a.y); u[2] = f2b(a.z); u[3] = f2b(a.w);
        u[4] = f2b(c.x); u[5] = f2b(c.y); u[6] = f2b(c.z); u[7] = f2b(c.w);
        wfrag[l][kk][n] = __builtin_bit_cast(bf16x8, u);
      }
  }
  __syncthreads();   // w0s/b0s/wls ready

  const int tl = tid >> 3;    // 0..63 (local t row)
  const int q  = tid & 7;     // d-chunk q*16..+15

  for (int it = 0; it < NIT; ++it) {
    u16* pCur = xP[it & 1];
    u16* pAlt = xP[(it & 1) ^ 1];

    // ---- layer 0 -> pCur ----
    {
      const float dom = (float)(it * 64 + tl) * (1.0f / (float)(T - 1));
      #pragma unroll
      for (int c = 0; c < 2; ++c) {
        const int d = q * 16 + c * 8;
        const float4 wa = *(const float4*)&w0s[d];
        const float4 wb = *(const float4*)&w0s[d + 4];
        const float4 ba = *(const float4*)&b0s[d];
        const float4 bb = *(const float4*)&b0s[d + 4];
        u16x8 p;
        p[0] = f2b(__sinf(wi * (wa.x * dom + ba.x)));
        p[1] = f2b(__sinf(wi * (wa.y * dom + ba.y)));
        p[2] = f2b(__sinf(wi * (wa.z * dom + ba.z)));
        p[3] = f2b(__sinf(wi * (wa.w * dom + ba.w)));
        p[4] = f2b(__sinf(wi * (wb.x * dom + bb.x)));
        p[5] = f2b(__sinf(wi * (wb.y * dom + bb.y)));
        p[6] = f2b(__sinf(wi * (wb.z * dom + bb.z)));
        p[7] = f2b(__sinf(wi * (wb.w * dom + bb.w)));
        *(u16x8*)&pCur[swz(tl, d)] = p;
      }
    }
    __syncthreads();   // (1) pCur = x0 ready

    f32x4 acc[2][2];

    // ---- hidden layer 1: acc = x0 . W1^T ----
    #pragma unroll
    for (int m = 0; m < 2; ++m)
      #pragma unroll
      for (int n = 0; n < 2; ++n) acc[m][n] = (f32x4){0.f, 0.f, 0.f, 0.f};
    #pragma unroll
    for (int kk = 0; kk < 4; ++kk) {
      const int kb = kk * 32 + lg * 8;
      bf16x8 ah[2];
      #pragma unroll
      for (int m = 0; m < 2; ++m)
        ah[m] = *(const bf16x8*)&pCur[swz(wt * 32 + m * 16 + lm, kb)];
      #pragma unroll
      for (int m = 0; m < 2; ++m)
        #pragma unroll
        for (int n = 0; n < 2; ++n)
          acc[m][n] = __builtin_amdgcn_mfma_f32_16x16x32_bf16(ah[m], wfrag[0][kk][n], acc[m][n], 0, 0, 0);
    }
    // ---- act1 -> pAlt (C/D: col=lm -> o, row=lg*4+r -> t) ----
    #pragma unroll
    for (int m = 0; m < 2; ++m)
      #pragma unroll
      for (int n = 0; n < 2; ++n) {
        const int o = wo * 32 + n * 16 + lm;
        #pragma unroll
        for (int r = 0; r < 4; ++r) {
          const int t = wt * 32 + m * 16 + lg * 4 + r;
          pAlt[swz(t, o)] = f2b(__sinf(acc[m][n][r] + bhv[0][n]));
        }
      }
    __syncthreads();   // (2) pAlt = x1 ready (all x0 reads done)

    // ---- hidden layer 2: acc = x1 . W2^T ----
    #pragma unroll
    for (int m = 0; m < 2; ++m)
      #pragma unroll
      for (int n = 0; n < 2; ++n) acc[m][n] = (f32x4){0.f, 0.f, 0.f, 0.f};
    #pragma unroll
    for (int kk = 0; kk < 4; ++kk) {
      const int kb = kk * 32 + lg * 8;
      bf16x8 ah[2];
      #pragma unroll
      for (int m = 0; m < 2; ++m)
        ah[m] = *(const bf16x8*)&pAlt[swz(wt * 32 + m * 16 + lm, kb)];
      #pragma unroll
      for (int m = 0; m < 2; ++m)
        #pragma unroll
        for (int n = 0; n < 2; ++n)
          acc[m][n] = __builtin_amdgcn_mfma_f32_16x16x32_bf16(ah[m], wfrag[1][kk][n], acc[m][n], 0, 0, 0);
    }
    // ---- act2 -> pCur (x0 reads finished at barrier 2) ----
    #pragma unroll
    for (int m = 0; m < 2; ++m)
      #pragma unroll
      for (int n = 0; n < 2; ++n) {
        const int o = wo * 32 + n * 16 + lm;
        #pragma unroll
        for (int r = 0; r < 4; ++r) {
          const int t = wt * 32 + m * 16 + lg * 4 + r;
          pCur[swz(t, o)] = f2b(__sinf(acc[m][n][r] + bhv[1][n]));
        }
      }
    __syncthreads();   // (3) pCur = x2 ready

    // ---- final: y[t] = Wl . x2[t,:] + bl ----
    {
      const int i = q * 16;
      float a = 0.0f;
      const bf16x8 h0 = *(const bf16x8*)&pCur[swz(tl, i)];
      const bf16x8 h1 = *(const bf16x8*)&pCur[swz(tl, i + 8)];
      const float4 wl0 = *(const float4*)&wls[i];
      const float4 wl1 = *(const float4*)&wls[i + 4];
      const float4 wl2 = *(const float4*)&wls[i + 8];
      const float4 wl3 = *(const float4*)&wls[i + 12];
      a += wl0.x * b2f((u16)h0[0]) + wl0.y * b2f((u16)h0[1])
         + wl0.z * b2f((u16)h0[2]) + wl0.w * b2f((u16)h0[3]);
      a += wl1.x * b2f((u16)h0[4]) + wl1.y * b2f((u16)h0[5])
         + wl1.z * b2f((u16)h0[6]) + wl1.w * b2f((u16)h0[7]);
      a += wl2.x * b2f((u16)h1[0]) + wl2.y * b2f((u16)h1[1])
         + wl2.z * b2f((u16)h1[2]) + wl2.w * b2f((u16)h1[3]);
      a += wl3.x * b2f((u16)h1[4]) + wl3.y * b2f((u16)h1[5])
         + wl3.z * b2f((u16)h1[6]) + wl3.w * b2f((u16)h1[7]);
      a += __shfl_xor(a, 1);
      a += __shfl_xor(a, 2);
      a += __shfl_xor(a, 4);
      if (q == 0)
        efn[(size_t)(it * 64 + tl) * EF_W + CCc + e] = a + blv;
    }
    // next-iter L0 writes the plane last read before barrier (3) -> safe
  }
}

// ---------------------------------------------------------------------------
__global__ void normalize_kernel(float* __restrict__ efn)
{
  const int t = blockIdx.x;
  const int c = threadIdx.x;   // 64
  float* row = efn + (size_t)t * EF_W;
  float v[16];
  float s = 1.0f;
  #pragma unroll
  for (int n = 0; n < 16; ++n) {
    v[n] = row[CCc + n * CCc + c];
    s += v[n] * v[n];
  }
  const float inv = 1.0f / sqrtf(s);
  row[c] = inv;
  #pragma unroll
  for (int n = 0; n < 16; ++n)
    row[CCc + n * CCc + c] = v[n] * inv;
}

// coeffs: block (n, b), 256 thr = 64 c x 4 t-chunks, LDS reduce.
__global__ __launch_bounds__(256) void coeffs_kernel(
    const float* __restrict__ x_enc, const float* __restrict__ x_mark_enc,
    const float* __restrict__ efn_in, float* __restrict__ flat_in)
{
  const int n  = blockIdx.x;   // 17
  const int b  = blockIdx.y;   // 32
  const int c  = threadIdx.x & 63;
  const int ch = threadIdx.x >> 6;   // 0..3
  __shared__ float red[4][64];
  float acc = 0.0f;
  #pragma unroll 4
  for (int t = ch * 128; t < ch * 128 + 128; ++t)
    acc += x_enc[((size_t)b * T_INc + t) * CCc + c]
         * efn_in[(size_t)t * EF_W + n * CCc + c];
  red[ch][c] = acc;
  __syncthreads();
  if (ch == 0) {
    acc += red[1][c] + red[2][c] + red[3][c];
    flat_in[b * LIN_I + n * CCc + c] = acc;
    if (n == 0 && c < 4)
      flat_in[b * LIN_I + EF_W + c] =
          x_mark_enc[((size_t)b * T_INc + (T_INc - 1)) * 4 + c];
  }
}

// Wlin transpose (for coalesced GEMV)
__global__ __launch_bounds__(256) void transpose_lin(const float* __restrict__ W,
                                                     float* __restrict__ Wt)
{
  __shared__ float tile[32][33];
  const int j0 = blockIdx.x * 32;
  const int o0 = blockIdx.y * 32;
  const int tx = threadIdx.x & 31, ty = threadIdx.x >> 5;  // ty 0..7
  #pragma unroll
  for (int r = 0; r < 32; r += 8) {
    const int o = o0 + ty + r, j = j0 + tx;
    tile[ty + r][tx] = (o < LIN_O && j < LIN_I) ? W[(size_t)o * LIN_I + j] : 0.f;
  }
  __syncthreads();
  #pragma unroll
  for (int r = 0; r < 32; r += 8) {
    const int j = j0 + ty + r, o = o0 + tx;
    if (j < LIN_I && o < LIN_O) Wt[(size_t)j * LIN_O + o] = tile[tx][ty + r];
  }
}

// linear (transposed W): block (o-tile, b), 256 thr = 64 o x 4 j-chunks.
__global__ __launch_bounds__(256) void linear_t_kernel(
    const float* __restrict__ flat_in, const float* __restrict__ Wt,
    const float* __restrict__ blin, float* __restrict__ pred)
{
  const int og = blockIdx.x;   // 17
  const int b  = blockIdx.y;   // 32
  const int c  = threadIdx.x & 63;
  const int ch = threadIdx.x >> 6;
  const int o  = og * 64 + c;
  __shared__ float red[4][64];
  const float* xi = flat_in + b * LIN_I;
  float acc = 0.0f;
  #pragma unroll 4
  for (int j = ch * 273; j < ch * 273 + 273; ++j)
    acc += Wt[(size_t)j * LIN_O + o] * xi[j];
  red[ch][c] = acc;
  __syncthreads();
  if (ch == 0)
    pred[b * LIN_O + o] = acc + red[1][c] + red[2][c] + red[3][c] + blin[o];
}

// fallback row-major linear (if ws too small for Wt)
__global__ void linear_row_kernel(const float* __restrict__ flat_in,
                                  const float* __restrict__ Wlin,
                                  const float* __restrict__ blin,
                                  float* __restrict__ pred)
{
  const int o = blockIdx.x * 64 + threadIdx.x;
  const int b = blockIdx.y;
  const float* w  = Wlin + (size_t)o * LIN_I;
  const float* xi = flat_in + b * LIN_I;
  float acc = blin[o];
  for (int j = 0; j < LIN_I; ++j) acc += w[j] * xi[j];
  pred[b * LIN_O + o] = acc;
}

__global__ void recon_kernel(const float* __restrict__ pred,
                             const float* __restrict__ efn_out,
                             float* __restrict__ out)
{
  const int b = blockIdx.y;
  const int t = blockIdx.x * 4 + (threadIdx.x >> 6);
  const int c = threadIdx.x & 63;
  float acc = 0.0f;
  #pragma unroll
  for (int n = 0; n < NB1; ++n)
    acc += pred[b * LIN_O + n * CCc + c]
         * efn_out[(size_t)t * EF_W + n * CCc + c];
  out[((size_t)b * T_OUTc + t) * CCc + c] = acc;
}

// ---------------------------------------------------------------------------
extern "C" void kernel_launch(void* const* d_in, const int* in_sizes, int n_in,
                              void* d_out, int out_size, void* d_ws, size_t ws_size,
                              hipStream_t stream)
{
  const float* x_enc      = (const float*)d_in[0];
  const float* x_mark_enc = (const float*)d_in[1];
  const float* W0_in  = (const float*)d_in[4];
  const float* b0_in  = (const float*)d_in[5];
  const float* Wh_in  = (const float*)d_in[6];
  const float* bh_in  = (const float*)d_in[7];
  const float* Wl_in  = (const float*)d_in[8];
  const float* bl_in  = (const float*)d_in[9];
  const float* w0i_in = (const float*)d_in[10];
  const float* W0_out  = (const float*)d_in[11];
  const float* b0_out  = (const float*)d_in[12];
  const float* Wh_out  = (const float*)d_in[13];
  const float* bh_out  = (const float*)d_in[14];
  const float* Wl_out  = (const float*)d_in[15];
  const float* bl_out  = (const float*)d_in[16];
  const float* w0i_out = (const float*)d_in[17];
  const float* Wlin = (const float*)d_in[18];
  const float* blin = (const float*)d_in[19];

  float* ws      = (float*)d_ws;
  float* efn_in  = ws;                                   // 512*1088
  float* efn_out = efn_in + (size_t)T_INc * EF_W;        // 256*1088
  float* flat_in = efn_out + (size_t)T_OUTc * EF_W;      // 32*1092
  float* pred    = flat_in + (size_t)BBc * LIN_I;        // 32*1088
  float* Wt      = pred + (size_t)BBc * LIN_O;           // 1092*1088
  const size_t needWt = ((size_t)(Wt - ws) + (size_t)LIN_I * LIN_O) * sizeof(float);
  const bool useWt = (ws_size >= needWt);

  eigen_persist<T_INc><<<dim3(E_TOT), dim3(512), 0, stream>>>(
      W0_in, b0_in, Wh_in, bh_in, Wl_in, bl_in, w0i_in, efn_in);
  eigen_persist<T_OUTc><<<dim3(E_TOT), dim3(512), 0, stream>>>(
      W0_out, b0_out, Wh_out, bh_out, Wl_out, bl_out, w0i_out, efn_out);

  normalize_kernel<<<dim3(T_INc),  dim3(64), 0, stream>>>(efn_in);
  normalize_kernel<<<dim3(T_OUTc), dim3(64), 0, stream>>>(efn_out);

  coeffs_kernel<<<dim3(NB1, BBc), dim3(256), 0, stream>>>(x_enc, x_mark_enc, efn_in, flat_in);

  if (useWt) {
    transpose_lin<<<dim3((LIN_I + 31) / 32, (LIN_O + 31) / 32), dim3(256), 0, stream>>>(Wlin, Wt);
    linear_t_kernel<<<dim3(NB1, BBc), dim3(256), 0, stream>>>(flat_in, Wt, blin, pred);
  } else {
    linear_row_kernel<<<dim3(NB1, BBc), dim3(64), 0, stream>>>(flat_in, Wlin, blin, pred);
  }

  recon_kernel<<<dim3(T_OUTc / 4, BBc), dim3(256), 0, stream>>>(pred, efn_out, (float*)d_out);
}

// Round 10
// 205.368 us; speedup vs baseline: 10.7188x; 1.2002x over previous
//
#include <hip/hip_runtime.h>
#include <hip/hip_bf16.h>
#include <math.h>

// SIREN eigenfunction banks + small linear head.
// eigen: persistent-e kernel, merged T_IN/T_OUT launch. W fragments in regs,
// ping-pong LDS x planes (swz key &15 -> conflict-free act writes),
// packed bf16 conversion via __float22bfloat162_rn (compiler cvt_pk).

typedef short  bf16x8 __attribute__((ext_vector_type(8)));
typedef float  f32x4  __attribute__((ext_vector_type(4)));
typedef unsigned short u16;
typedef u16    u16x8  __attribute__((ext_vector_type(8)));
typedef unsigned int u32;
typedef u32    u32x4  __attribute__((ext_vector_type(4)));

constexpr int DD    = 128;
constexpr int E_TOT = 1024;
constexpr int T_INc = 512;
constexpr int T_OUTc= 256;
constexpr int BBc   = 32;
constexpr int CCc   = 64;
constexpr int NB1   = 17;
constexpr int EF_W  = NB1 * CCc;     // 1088
constexpr int LIN_I = EF_W + 4;      // 1092
constexpr int LIN_O = EF_W;          // 1088

__device__ __forceinline__ u16 f2b(float f) {          // bf16 RNE (proven)
  unsigned u = __builtin_bit_cast(unsigned, f);
  return (u16)((u + 0x7FFFu + ((u >> 16) & 1u)) >> 16);
}
__device__ __forceinline__ float b2f(u16 u) {
  unsigned v = ((unsigned)u) << 16;
  return __builtin_bit_cast(float, v);
}
// packed RNE pair via compiler intrinsic: low 16 bits = cvt(a), high = cvt(b)
__device__ __forceinline__ u32 pkrn(float a, float b) {
  __hip_bfloat162 h = __float22bfloat162_rn(float2{a, b});
  u32 r;
  __builtin_memcpy(&r, &h, 4);
  return r;
}

// XOR-swizzled element index into a row-major [rows][128] u16 LDS plane.
// byte = row*256 + ((col*2) ^ ((row&15)<<4)); 16B-chunk preserving.
__device__ __forceinline__ int swz(int row, int col) {
  return row * DD + ((((col << 1) ^ ((row & 15) << 4)) >> 1));
}

// ---------------------------------------------------------------------------
// eigen_persist: grid = 2*E_TOT. Blocks [0,1024): T_IN; [1024,2048): T_OUT.
// 8 waves = (wt 0..1) x (wo 0..3), wave tile 32t x 32o per 64-t iteration.
// ---------------------------------------------------------------------------
__global__ __launch_bounds__(512, 4) void eigen_persist(
    const float* __restrict__ W0i, const float* __restrict__ b0i,
    const float* __restrict__ Whi, const float* __restrict__ bhi,
    const float* __restrict__ Wli, const float* __restrict__ bli,
    const float* __restrict__ w0ii, float* __restrict__ efni,
    const float* __restrict__ W0o, const float* __restrict__ b0o,
    const float* __restrict__ Who, const float* __restrict__ bho,
    const float* __restrict__ Wlo, const float* __restrict__ blo,
    const float* __restrict__ w0io, float* __restrict__ efno)
{
  __shared__ u16 xP[2][8192];          // two 64x128 bf16 planes (swizzled)
  __shared__ float w0s[128], b0s[128], wls[128];

  const bool isIn = (blockIdx.x < E_TOT);
  const int  e    = blockIdx.x & (E_TOT - 1);
  const int  NIT  = isIn ? (T_INc / 64) : (T_OUTc / 64);
  const float tstep = isIn ? (1.0f / (float)(T_INc - 1)) : (1.0f / (float)(T_OUTc - 1));
  const float* W0 = isIn ? W0i : W0o;
  const float* b0 = isIn ? b0i : b0o;
  const float* Wh = isIn ? Whi : Who;
  const float* bh = isIn ? bhi : bho;
  const float* Wl = isIn ? Wli : Wlo;
  const float* bl = isIn ? bli : blo;
  const float* w0i = isIn ? w0ii : w0io;
  float* efn = isIn ? efni : efno;

  const int tid  = threadIdx.x;
  const int lane = tid & 63;
  const int wv   = tid >> 6;      // wave 0..7
  const int wt   = wv >> 2;       // t-group: rows wt*32..+32
  const int wo   = wv & 3;        // o-group: cols wo*32..+32
  const int lm   = lane & 15;
  const int lg   = lane >> 4;

  // ---- stage small per-e vectors to LDS ----
  if (tid < 128)       w0s[tid]       = W0[(size_t)e * DD + tid];
  else if (tid < 256)  b0s[tid - 128] = b0[(size_t)e * DD + tid - 128];
  else if (tid < 384)  wls[tid - 256] = Wl[(size_t)e * DD + tid - 256];
  const float wi  = w0i[e];
  const float blv = bl[e];

  // ---- bias preload (per-lane o = wo*32 + n*16 + lm) ----
  float bhv[2][2];
  #pragma unroll
  for (int l = 0; l < 2; ++l)
    #pragma unroll
    for (int n = 0; n < 2; ++n)
      bhv[l][n] = bh[((size_t)l * E_TOT + e) * DD + wo * 32 + n * 16 + lm];

  // ---- W fragments: global fp32 -> bf16 regs (held across all iterations).
  // B-frag (proven): lane(lm,lg) holds W[o = wo*32+n*16+lm][k = kk*32+lg*8..+7]
  bf16x8 wfrag[2][4][2];
  #pragma unroll
  for (int l = 0; l < 2; ++l) {
    const float* Wg = Wh + ((size_t)l * E_TOT + e) * (DD * DD);
    #pragma unroll
    for (int kk = 0; kk < 4; ++kk)
      #pragma unroll
      for (int n = 0; n < 2; ++n) {
        const float* p = Wg + (wo * 32 + n * 16 + lm) * DD + kk * 32 + lg * 8;
        const float4 a = *(const float4*)p;
        const float4 c = *(const float4*)(p + 4);
        u32x4 u;
        u[0] = pkrn(a.x, a.y);
        u[1] = pkrn(a.z, a.w);
        u[2] = pkrn(c.x, c.y);
        u[3] = pkrn(c.z, c.w);
        wfrag[l][kk][n] = __builtin_bit_cast(bf16x8, u);
      }
  }
  __syncthreads();   // w0s/b0s/wls ready

  const int tl = tid >> 3;    // 0..63 (local t row)
  const int q  = tid & 7;     // d-chunk q*16..+15

  for (int it = 0; it < NIT; ++it) {
    u16* pCur = xP[it & 1];
    u16* pAlt = xP[(it & 1) ^ 1];

    // ---- layer 0 -> pCur ----
    {
      const float dom = (float)(it * 64 + tl) * tstep;
      #pragma unroll
      for (int c = 0; c < 2; ++c) {
        const int d = q * 16 + c * 8;
        const float4 wa = *(const float4*)&w0s[d];
        const float4 wb = *(const float4*)&w0s[d + 4];
        const float4 ba = *(const float4*)&b0s[d];
        const float4 bb = *(const float4*)&b0s[d + 4];
        u32x4 u;
        u[0] = pkrn(__sinf(wi * (wa.x * dom + ba.x)), __sinf(wi * (wa.y * dom + ba.y)));
        u[1] = pkrn(__sinf(wi * (wa.z * dom + ba.z)), __sinf(wi * (wa.w * dom + ba.w)));
        u[2] = pkrn(__sinf(wi * (wb.x * dom + bb.x)), __sinf(wi * (wb.y * dom + bb.y)));
        u[3] = pkrn(__sinf(wi * (wb.z * dom + bb.z)), __sinf(wi * (wb.w * dom + bb.w)));
        *(u16x8*)&pCur[swz(tl, d)] = __builtin_bit_cast(u16x8, u);
      }
    }
    __syncthreads();   // (1) pCur = x0 ready

    f32x4 acc[2][2];

    // ---- hidden layer 1: acc = x0 . W1^T ----
    #pragma unroll
    for (int m = 0; m < 2; ++m)
      #pragma unroll
      for (int n = 0; n < 2; ++n) acc[m][n] = (f32x4){0.f, 0.f, 0.f, 0.f};
    #pragma unroll
    for (int kk = 0; kk < 4; ++kk) {
      const int kb = kk * 32 + lg * 8;
      bf16x8 ah[2];
      #pragma unroll
      for (int m = 0; m < 2; ++m)
        ah[m] = *(const bf16x8*)&pCur[swz(wt * 32 + m * 16 + lm, kb)];
      #pragma unroll
      for (int m = 0; m < 2; ++m)
        #pragma unroll
        for (int n = 0; n < 2; ++n)
          acc[m][n] = __builtin_amdgcn_mfma_f32_16x16x32_bf16(ah[m], wfrag[0][kk][n], acc[m][n], 0, 0, 0);
    }
    // ---- act1 -> pAlt (C/D: col=lm -> o, row=lg*4+r -> t) ----
    #pragma unroll
    for (int m = 0; m < 2; ++m)
      #pragma unroll
      for (int n = 0; n < 2; ++n) {
        const int o = wo * 32 + n * 16 + lm;
        const int t = wt * 32 + m * 16 + lg * 4;
        const u32 p0 = pkrn(__sinf(acc[m][n][0] + bhv[0][n]), __sinf(acc[m][n][1] + bhv[0][n]));
        const u32 p1 = pkrn(__sinf(acc[m][n][2] + bhv[0][n]), __sinf(acc[m][n][3] + bhv[0][n]));
        pAlt[swz(t + 0, o)] = (u16)p0;
        pAlt[swz(t + 1, o)] = (u16)(p0 >> 16);
        pAlt[swz(t + 2, o)] = (u16)p1;
        pAlt[swz(t + 3, o)] = (u16)(p1 >> 16);
      }
    __syncthreads();   // (2) pAlt = x1 ready (all x0 reads done)

    // ---- hidden layer 2: acc = x1 . W2^T ----
    #pragma unroll
    for (int m = 0; m < 2; ++m)
      #pragma unroll
      for (int n = 0; n < 2; ++n) acc[m][n] = (f32x4){0.f, 0.f, 0.f, 0.f};
    #pragma unroll
    for (int kk = 0; kk < 4; ++kk) {
      const int kb = kk * 32 + lg * 8;
      bf16x8 ah[2];
      #pragma unroll
      for (int m = 0; m < 2; ++m)
        ah[m] = *(const bf16x8*)&pAlt[swz(wt * 32 + m * 16 + lm, kb)];
      #pragma unroll
      for (int m = 0; m < 2; ++m)
        #pragma unroll
        for (int n = 0; n < 2; ++n)
          acc[m][n] = __builtin_amdgcn_mfma_f32_16x16x32_bf16(ah[m], wfrag[1][kk][n], acc[m][n], 0, 0, 0);
    }
    // ---- act2 -> pCur (x0 reads finished at barrier 2) ----
    #pragma unroll
    for (int m = 0; m < 2; ++m)
      #pragma unroll
      for (int n = 0; n < 2; ++n) {
        const int o = wo * 32 + n * 16 + lm;
        const int t = wt * 32 + m * 16 + lg * 4;
        const u32 p0 = pkrn(__sinf(acc[m][n][0] + bhv[1][n]), __sinf(acc[m][n][1] + bhv[1][n]));
        const u32 p1 = pkrn(__sinf(acc[m][n][2] + bhv[1][n]), __sinf(acc[m][n][3] + bhv[1][n]));
        pCur[swz(t + 0, o)] = (u16)p0;
        pCur[swz(t + 1, o)] = (u16)(p0 >> 16);
        pCur[swz(t + 2, o)] = (u16)p1;
        pCur[swz(t + 3, o)] = (u16)(p1 >> 16);
      }
    __syncthreads();   // (3) pCur = x2 ready

    // ---- final: y[t] = Wl . x2[t,:] + bl ----
    {
      const int i = q * 16;
      float a = 0.0f;
      const bf16x8 h0 = *(const bf16x8*)&pCur[swz(tl, i)];
      const bf16x8 h1 = *(const bf16x8*)&pCur[swz(tl, i + 8)];
      const float4 wl0 = *(const float4*)&wls[i];
      const float4 wl1 = *(const float4*)&wls[i + 4];
      const float4 wl2 = *(const float4*)&wls[i + 8];
      const float4 wl3 = *(const float4*)&wls[i + 12];
      a += wl0.x * b2f((u16)h0[0]) + wl0.y * b2f((u16)h0[1])
         + wl0.z * b2f((u16)h0[2]) + wl0.w * b2f((u16)h0[3]);
      a += wl1.x * b2f((u16)h0[4]) + wl1.y * b2f((u16)h0[5])
         + wl1.z * b2f((u16)h0[6]) + wl1.w * b2f((u16)h0[7]);
      a += wl2.x * b2f((u16)h1[0]) + wl2.y * b2f((u16)h1[1])
         + wl2.z * b2f((u16)h1[2]) + wl2.w * b2f((u16)h1[3]);
      a += wl3.x * b2f((u16)h1[4]) + wl3.y * b2f((u16)h1[5])
         + wl3.z * b2f((u16)h1[6]) + wl3.w * b2f((u16)h1[7]);
      a += __shfl_xor(a, 1);
      a += __shfl_xor(a, 2);
      a += __shfl_xor(a, 4);
      if (q == 0)
        efn[(size_t)(it * 64 + tl) * EF_W + CCc + e] = a + blv;
    }
    // next-iter L0 writes the plane last read before barrier (3) -> safe
  }
}

// ---------------------------------------------------------------------------
__global__ void normalize_kernel(float* __restrict__ efn)
{
  const int t = blockIdx.x;
  const int c = threadIdx.x;   // 64
  float* row = efn + (size_t)t * EF_W;
  float v[16];
  float s = 1.0f;
  #pragma unroll
  for (int n = 0; n < 16; ++n) {
    v[n] = row[CCc + n * CCc + c];
    s += v[n] * v[n];
  }
  const float inv = 1.0f / sqrtf(s);
  row[c] = inv;
  #pragma unroll
  for (int n = 0; n < 16; ++n)
    row[CCc + n * CCc + c] = v[n] * inv;
}

// coeffs: block (n, b), 512 thr = 64 c x 8 t-chunks, LDS reduce.
__global__ __launch_bounds__(512) void coeffs_kernel(
    const float* __restrict__ x_enc, const float* __restrict__ x_mark_enc,
    const float* __restrict__ efn_in, float* __restrict__ flat_in)
{
  const int n  = blockIdx.x;   // 17
  const int b  = blockIdx.y;   // 32
  const int c  = threadIdx.x & 63;
  const int ch = threadIdx.x >> 6;   // 0..7
  __shared__ float red[8][64];
  float acc = 0.0f;
  #pragma unroll 4
  for (int t = ch * 64; t < ch * 64 + 64; ++t)
    acc += x_enc[((size_t)b * T_INc + t) * CCc + c]
         * efn_in[(size_t)t * EF_W + n * CCc + c];
  red[ch][c] = acc;
  __syncthreads();
  if (ch == 0) {
    #pragma unroll
    for (int k = 1; k < 8; ++k) acc += red[k][c];
    flat_in[b * LIN_I + n * CCc + c] = acc;
    if (n == 0 && c < 4)
      flat_in[b * LIN_I + EF_W + c] =
          x_mark_enc[((size_t)b * T_INc + (T_INc - 1)) * 4 + c];
  }
}

// Wlin transpose (for coalesced GEMV)
__global__ __launch_bounds__(256) void transpose_lin(const float* __restrict__ W,
                                                     float* __restrict__ Wt)
{
  __shared__ float tile[32][33];
  const int j0 = blockIdx.x * 32;
  const int o0 = blockIdx.y * 32;
  const int tx = threadIdx.x & 31, ty = threadIdx.x >> 5;  // ty 0..7
  #pragma unroll
  for (int r = 0; r < 32; r += 8) {
    const int o = o0 + ty + r, j = j0 + tx;
    tile[ty + r][tx] = (o < LIN_O && j < LIN_I) ? W[(size_t)o * LIN_I + j] : 0.f;
  }
  __syncthreads();
  #pragma unroll
  for (int r = 0; r < 32; r += 8) {
    const int j = j0 + ty + r, o = o0 + tx;
    if (j < LIN_I && o < LIN_O) Wt[(size_t)j * LIN_O + o] = tile[tx][ty + r];
  }
}

// linear (transposed W): block (o-tile, b), 256 thr = 64 o x 4 j-chunks.
__global__ __launch_bounds__(256) void linear_t_kernel(
    const float* __restrict__ flat_in, const float* __restrict__ Wt,
    const float* __restrict__ blin, float* __restrict__ pred)
{
  const int og = blockIdx.x;   // 17
  const int b  = blockIdx.y;   // 32
  const int c  = threadIdx.x & 63;
  const int ch = threadIdx.x >> 6;
  const int o  = og * 64 + c;
  __shared__ float red[4][64];
  const float* xi = flat_in + b * LIN_I;
  float acc = 0.0f;
  #pragma unroll 4
  for (int j = ch * 273; j < ch * 273 + 273; ++j)
    acc += Wt[(size_t)j * LIN_O + o] * xi[j];
  red[ch][c] = acc;
  __syncthreads();
  if (ch == 0)
    pred[b * LIN_O + o] = acc + red[1][c] + red[2][c] + red[3][c] + blin[o];
}

// fallback row-major linear (if ws too small for Wt)
__global__ void linear_row_kernel(const float* __restrict__ flat_in,
                                  const float* __restrict__ Wlin,
                                  const float* __restrict__ blin,
                                  float* __restrict__ pred)
{
  const int o = blockIdx.x * 64 + threadIdx.x;
  const int b = blockIdx.y;
  const float* w  = Wlin + (size_t)o * LIN_I;
  const float* xi = flat_in + b * LIN_I;
  float acc = blin[o];
  for (int j = 0; j < LIN_I; ++j) acc += w[j] * xi[j];
  pred[b * LIN_O + o] = acc;
}

__global__ void recon_kernel(const float* __restrict__ pred,
                             const float* __restrict__ efn_out,
                             float* __restrict__ out)
{
  const int b = blockIdx.y;
  const int t = blockIdx.x * 4 + (threadIdx.x >> 6);
  const int c = threadIdx.x & 63;
  float acc = 0.0f;
  #pragma unroll
  for (int n = 0; n < NB1; ++n)
    acc += pred[b * LIN_O + n * CCc + c]
         * efn_out[(size_t)t * EF_W + n * CCc + c];
  out[((size_t)b * T_OUTc + t) * CCc + c] = acc;
}

// ---------------------------------------------------------------------------
extern "C" void kernel_launch(void* const* d_in, const int* in_sizes, int n_in,
                              void* d_out, int out_size, void* d_ws, size_t ws_size,
                              hipStream_t stream)
{
  const float* x_enc      = (const float*)d_in[0];
  const float* x_mark_enc = (const float*)d_in[1];
  const float* W0_in  = (const float*)d_in[4];
  const float* b0_in  = (const float*)d_in[5];
  const float* Wh_in  = (const float*)d_in[6];
  const float* bh_in  = (const float*)d_in[7];
  const float* Wl_in  = (const float*)d_in[8];
  const float* bl_in  = (const float*)d_in[9];
  const float* w0i_in = (const float*)d_in[10];
  const float* W0_out  = (const float*)d_in[11];
  const float* b0_out  = (const float*)d_in[12];
  const float* Wh_out  = (const float*)d_in[13];
  const float* bh_out  = (const float*)d_in[14];
  const float* Wl_out  = (const float*)d_in[15];
  const float* bl_out  = (const float*)d_in[16];
  const float* w0i_out = (const float*)d_in[17];
  const float* Wlin = (const float*)d_in[18];
  const float* blin = (const float*)d_in[19];

  float* ws      = (float*)d_ws;
  float* efn_in  = ws;                                   // 512*1088
  float* efn_out = efn_in + (size_t)T_INc * EF_W;        // 256*1088
  float* flat_in = efn_out + (size_t)T_OUTc * EF_W;      // 32*1092
  float* pred    = flat_in + (size_t)BBc * LIN_I;        // 32*1088
  float* Wt      = pred + (size_t)BBc * LIN_O;           // 1092*1088
  const size_t needWt = ((size_t)(Wt - ws) + (size_t)LIN_I * LIN_O) * sizeof(float);
  const bool useWt = (ws_size >= needWt);

  eigen_persist<<<dim3(2 * E_TOT), dim3(512), 0, stream>>>(
      W0_in, b0_in, Wh_in, bh_in, Wl_in, bl_in, w0i_in, efn_in,
      W0_out, b0_out, Wh_out, bh_out, Wl_out, bl_out, w0i_out, efn_out);

  normalize_kernel<<<dim3(T_INc),  dim3(64), 0, stream>>>(efn_in);
  normalize_kernel<<<dim3(T_OUTc), dim3(64), 0, stream>>>(efn_out);

  coeffs_kernel<<<dim3(NB1, BBc), dim3(512), 0, stream>>>(x_enc, x_mark_enc, efn_in, flat_in);

  if (useWt) {
    transpose_lin<<<dim3((LIN_I + 31) / 32, (LIN_O + 31) / 32), dim3(256), 0, stream>>>(Wlin, Wt);
    linear_t_kernel<<<dim3(NB1, BBc), dim3(256), 0, stream>>>(flat_in, Wt, blin, pred);
  } else {
    linear_row_kernel<<<dim3(NB1, BBc), dim3(64), 0, stream>>>(flat_in, Wlin, blin, pred);
  }

  recon_kernel<<<dim3(T_OUTc / 4, BBc), dim3(256), 0, stream>>>(pred, efn_out, (float*)d_out);
}